// Round 14
// baseline (3451.680 us; speedup 1.0000x reference)
//
#include <hip/hip_runtime.h>
#include <math.h>

#define EPSF 1e-8f

constexpr int CB = 16;      // batch
constexpr int CT = 1024;    // time
constexpr int CN = 512;     // nodes
constexpr int CD = 512;     // hidden
constexpr int CIN = 1536;   // 3*N
constexpr int PB = CN * CN;
constexpr size_t SBTN = (size_t)CB * CT * CN;
constexpr size_t SBNN = (size_t)CB * PB;
constexpr long long PLX = 16777216LL;   // Xtp plane stride (u16 elems)

typedef __attribute__((ext_vector_type(8))) short bf16x8;
typedef __attribute__((ext_vector_type(4))) float f32x4;

__device__ inline unsigned short f2bf(float x) {   // RNE to bf16
  unsigned u = __float_as_uint(x);
  unsigned r = (u + 0x7fffu + ((u >> 16) & 1u)) >> 16;
  return (unsigned short)r;
}
__device__ inline float bf2f(unsigned short h) { return __uint_as_float(((unsigned)h) << 16); }

// ---------------- utility ----------------
__global__ void zero_k(float* p, int n) {
  int i = blockIdx.x * 256 + threadIdx.x;
  if (i < n) p[i] = 0.f;
}

// ---------------- column means ----------------
__global__ __launch_bounds__(256) void colmean_k(const float* __restrict__ x, float* __restrict__ ms) {
  int b = blockIdx.y;
  int n = blockIdx.x * 256 + threadIdx.x;
  int t0 = blockIdx.z * 256;
  const float* xb = x + (size_t)b * CT * CN + (size_t)t0 * CN + n;
  float s = 0.f;
  for (int t = 0; t < 256; ++t) s += xb[(size_t)t * CN];
  atomicAdd(&ms[b * CN + n], s);
}

// ---------------- centered transpose-pack: x (b,t,n) -> Xtp slot b (n,t) bf16 hi/lo ----------------
__global__ __launch_bounds__(256) void cpack_k(const float* __restrict__ x, const float* __restrict__ ms,
                                               unsigned short* __restrict__ Xtp) {
  __shared__ float t[64][65];
  int b = blockIdx.z, n0 = blockIdx.x * 64, t0 = blockIdx.y * 64;
  const float* xb = x + (size_t)b * CT * CN;
  for (int idx = threadIdx.x; idx < 4096; idx += 256) {
    int r = idx >> 6, c = idx & 63;
    t[r][c] = xb[(size_t)(t0 + r) * CN + n0 + c] - ms[b * CN + n0 + c] * (1.0f / CT);
  }
  __syncthreads();
  unsigned short* base = Xtp + (size_t)b * 524288;
  for (int idx = threadIdx.x; idx < 2048; idx += 256) {
    int nr = idx >> 5, tc = (idx & 31) * 2;
    float v0 = t[tc][nr], v1 = t[tc + 1][nr];
    unsigned short h0 = f2bf(v0), h1 = f2bf(v1);
    unsigned short l0 = f2bf(v0 - bf2f(h0)), l1 = f2bf(v1 - bf2f(h1));
    size_t off = (size_t)(n0 + nr) * 1024 + t0 + tc;
    *(unsigned int*)&base[off] = (unsigned int)h0 | ((unsigned int)h1 << 16);
    *(unsigned int*)&base[off + PLX] = (unsigned int)l0 | ((unsigned int)l1 << 16);
  }
}

// ---------------- Spearman ranks: merge-split bitonic (run-granularity) ----------------
static __device__ inline unsigned long long shflx64(unsigned long long v, int m) {
  int lo = __shfl_xor((int)(unsigned)v, m, 64);
  int hi = __shfl_xor((int)(unsigned)(v >> 32), m, 64);
  return ((unsigned long long)(unsigned)hi << 32) | (unsigned)lo;
}

__global__ __launch_bounds__(256) void ranks_k(const float* __restrict__ x, unsigned short* __restrict__ Xtp) {
  int b = blockIdx.y;
  int n0 = blockIdx.x * 4;
  __shared__ float stage[4][1032];
  const float* xb = x + (size_t)b * CT * CN + n0;
  for (int t = threadIdx.x; t < 1024; t += 256) {
    float4 v = *(const float4*)&xb[(size_t)t * CN];
    stage[0][t] = v.x; stage[1][t] = v.y; stage[2][t] = v.z; stage[3][t] = v.w;
  }
  __syncthreads();
  const int c = threadIdx.x >> 6;
  const int lane = threadIdx.x & 63;
  unsigned long long kv[16];
#pragma unroll
  for (int m = 0; m < 16; ++m) {
    int pos = m * 64 + lane;
    unsigned int u = __float_as_uint(stage[c][pos]);
    u = (u & 0x80000000u) ? ~u : (u | 0x80000000u);
    kv[m] = (((unsigned long long)u) << 32) | (unsigned)pos;
  }
#define CE_KV(a, bb, up) { bool sw_ = (up) ? (kv[a] > kv[bb]) : (kv[a] < kv[bb]); \
  if (sw_) { unsigned long long t_ = kv[a]; kv[a] = kv[bb]; kv[bb] = t_; } }
  // phase 1: in-lane bitonic sort of 16 (ascending), pure VALU
#pragma unroll
  for (int k2 = 2; k2 <= 16; k2 <<= 1) {
#pragma unroll
    for (int j2 = 8; j2 >= 1; j2 >>= 1) {
      if (j2 >= k2) continue;
#pragma unroll
      for (int t = 0; t < 16; ++t)
        if (!(t & j2)) { bool up2 = ((t & k2) == 0); CE_KV(t, t | j2, up2); }
    }
  }
  // phase 2: bitonic network over 64 sorted runs; CE = merge-split
#pragma unroll
  for (int k = 2; k <= 64; k <<= 1) {
#pragma unroll
    for (int j = 32; j >= 1; j >>= 1) {
      if (j >= k) continue;
      bool up = ((lane & k) == 0);
      bool isLow = ((lane & j) == 0);
      bool keepMin = (isLow == up);
      unsigned long long oth[16];
#pragma unroll
      for (int i = 0; i < 16; ++i) oth[i] = shflx64(kv[15 - i], j);
#pragma unroll
      for (int i = 0; i < 16; ++i) {
        unsigned long long o = oth[i];
        bool less = kv[i] < o;
        kv[i] = (less == keepMin) ? kv[i] : o;
      }
#pragma unroll
      for (int j2 = 8; j2 >= 1; j2 >>= 1)
#pragma unroll
        for (int t = 0; t < 16; ++t)
          if (!(t & j2)) CE_KV(t, t | j2, true);
    }
  }
#undef CE_KV
#pragma unroll
  for (int m = 0; m < 16; ++m) {
    unsigned int pos = (unsigned int)kv[m] & 1023u;
    stage[c][pos] = ((float)(lane * 16 + m + 1) - 512.5f) * (1.0f / 512.0f);
  }
  __syncthreads();
  unsigned short* base = Xtp + (size_t)(16 + b) * 524288;
  for (int idx = threadIdx.x; idx < 2048; idx += 256) {
    int row = idx >> 9, t2 = (idx & 511) * 2;
    float v0 = stage[row][t2], v1 = stage[row][t2 + 1];
    unsigned short h0 = f2bf(v0), h1 = f2bf(v1);
    unsigned short l0 = f2bf(v0 - bf2f(h0)), l1 = f2bf(v1 - bf2f(h1));
    size_t off = (size_t)(n0 + row) * 1024 + t2;
    *(unsigned int*)&base[off] = (unsigned int)h0 | ((unsigned int)h1 << 16);
    *(unsigned int*)&base[off + PLX] = (unsigned int)l0 | ((unsigned int)l1 << 16);
  }
}

// ---------------- generic fp32 tiled GEMM (64x64 tile) + pair batching ----------------
template<bool TA, bool TB, bool ACC, bool RELU, bool SYRK = false>
__global__ __launch_bounds__(256) void gemm_k(
    const float* __restrict__ A, const float* __restrict__ B,
    const float* __restrict__ bias, float* __restrict__ C,
    int M, int Nc, int K, int lda, int ldb, int ldc,
    long long sA, long long sB, long long sC, float alpha,
    int pairs, long long pA, long long pB, long long pC) {
  __shared__ float As[16][68];
  __shared__ float Bs[16][68];
  const int bz = blockIdx.z;
  const int b = bz / pairs;
  const int p = bz - b * pairs;
  A += (size_t)b * sA + (size_t)p * pA;
  B += (size_t)b * sB + (size_t)p * pB;
  C += (size_t)b * sC + (size_t)p * pC;
  const int n0 = blockIdx.x * 64;
  const int m0 = blockIdx.y * 64;
  const int tid = threadIdx.x;
  const int tn = (tid & 15) * 4;
  const int tm = (tid >> 4) * 4;
  float acc[4][4];
#pragma unroll
  for (int i = 0; i < 4; ++i)
#pragma unroll
    for (int j = 0; j < 4; ++j) acc[i][j] = 0.f;

  const int kbeg = SYRK ? (m0 > n0 ? m0 : n0) : 0;
  for (int k0 = kbeg; k0 < K; k0 += 16) {
    if (TA) {
      const int lk = tid >> 4;
      const int lm = (tid & 15) * 4;
      const float4 v = *(const float4*)&A[(size_t)(k0 + lk) * lda + m0 + lm];
      *(float4*)&As[lk][lm] = v;
    } else {
      const int lm = tid >> 2;
      const int lk = (tid & 3) * 4;
      const float4 v = *(const float4*)&A[(size_t)(m0 + lm) * lda + k0 + lk];
      As[lk + 0][lm] = v.x; As[lk + 1][lm] = v.y; As[lk + 2][lm] = v.z; As[lk + 3][lm] = v.w;
    }
    if (TB) {
      const int ln = tid >> 2;
      const int lk = (tid & 3) * 4;
      const float4 v = *(const float4*)&B[(size_t)(n0 + ln) * ldb + k0 + lk];
      Bs[lk + 0][ln] = v.x; Bs[lk + 1][ln] = v.y; Bs[lk + 2][ln] = v.z; Bs[lk + 3][ln] = v.w;
    } else {
      const int lk = tid >> 4;
      const int ln = (tid & 15) * 4;
      const float4 v = *(const float4*)&B[(size_t)(k0 + lk) * ldb + n0 + ln];
      *(float4*)&Bs[lk][ln] = v;
    }
    __syncthreads();
#pragma unroll
    for (int kk = 0; kk < 16; ++kk) {
      const float4 a4 = *(const float4*)&As[kk][tm];
      const float4 b4 = *(const float4*)&Bs[kk][tn];
      const float av[4] = {a4.x, a4.y, a4.z, a4.w};
      const float bv[4] = {b4.x, b4.y, b4.z, b4.w};
#pragma unroll
      for (int i = 0; i < 4; ++i)
#pragma unroll
        for (int j = 0; j < 4; ++j) acc[i][j] = fmaf(av[i], bv[j], acc[i][j]);
    }
    __syncthreads();
  }
  float4 bb = make_float4(0.f, 0.f, 0.f, 0.f);
  if (bias) bb = *(const float4*)&bias[n0 + tn];
#pragma unroll
  for (int i = 0; i < 4; ++i) {
    size_t off = (size_t)(m0 + tm + i) * ldc + (n0 + tn);
    float4 v;
    v.x = alpha * acc[i][0] + bb.x;
    v.y = alpha * acc[i][1] + bb.y;
    v.z = alpha * acc[i][2] + bb.z;
    v.w = alpha * acc[i][3] + bb.w;
    if (ACC) {
      const float4 c0 = *(const float4*)&C[off];
      v.x += c0.x; v.y += c0.y; v.z += c0.z; v.w += c0.w;
    }
    if (RELU) {
      v.x = fmaxf(v.x, 0.f); v.y = fmaxf(v.y, 0.f);
      v.z = fmaxf(v.z, 0.f); v.w = fmaxf(v.w, 0.f);
    }
    *(float4*)&C[off] = v;
  }
}

// ---------------- bf16-split MFMA GEMM (128M x 128N tile, wave 64x64, K-step 32) ----------------
template<bool OUTF32, bool RELU, bool BIASROW>
__global__ __launch_bounds__(256, 2) void gemm_mfma(
    const unsigned short* __restrict__ A, const unsigned short* __restrict__ B,
    const float* __restrict__ bias, void* __restrict__ Cv,
    int K, int lda, int ldb, int ldc,
    long long sA, long long sB, long long sC,
    long long plA, long long plB, long long plC, float alpha) {
  __shared__ unsigned short As[2][4][128][8];
  __shared__ unsigned short Bs[2][4][128][8];
  const int bz = blockIdx.z;
  A += (size_t)bz * sA;
  B += (size_t)bz * sB;
  const int n0 = blockIdx.x * 128;
  const int m0 = blockIdx.y * 128;
  const int tid = threadIdx.x;
  const int wave = tid >> 6, lane = tid & 63;
  const int wm = wave & 1, wn = wave >> 1;
  const int l15 = lane & 15, quad = lane >> 4;
  const int r2 = tid >> 1;
  const int sp = (tid & 1) * 2;
  f32x4 acc[4][4];
#pragma unroll
  for (int i = 0; i < 4; ++i)
#pragma unroll
    for (int j = 0; j < 4; ++j) acc[i][j] = (f32x4){0.f, 0.f, 0.f, 0.f};

  for (int k0 = 0; k0 < K; k0 += 32) {
    const unsigned short* sa = A + (size_t)(m0 + r2) * lda + k0 + sp * 8;
    const unsigned short* sb = B + (size_t)(n0 + r2) * ldb + k0 + sp * 8;
    *(bf16x8*)&As[0][sp][r2][0]     = *(const bf16x8*)sa;
    *(bf16x8*)&As[0][sp + 1][r2][0] = *(const bf16x8*)(sa + 8);
    *(bf16x8*)&As[1][sp][r2][0]     = *(const bf16x8*)(sa + plA);
    *(bf16x8*)&As[1][sp + 1][r2][0] = *(const bf16x8*)(sa + plA + 8);
    *(bf16x8*)&Bs[0][sp][r2][0]     = *(const bf16x8*)sb;
    *(bf16x8*)&Bs[0][sp + 1][r2][0] = *(const bf16x8*)(sb + 8);
    *(bf16x8*)&Bs[1][sp][r2][0]     = *(const bf16x8*)(sb + plB);
    *(bf16x8*)&Bs[1][sp + 1][r2][0] = *(const bf16x8*)(sb + plB + 8);
    __syncthreads();
    bf16x8 ah[4], al[4], bh[4], bl[4];
#pragma unroll
    for (int i = 0; i < 4; ++i) {
      int m_l = wm * 64 + i * 16 + l15;
      int n_l = wn * 64 + i * 16 + l15;
      ah[i] = *(const bf16x8*)&As[0][quad][m_l][0];
      al[i] = *(const bf16x8*)&As[1][quad][m_l][0];
      bh[i] = *(const bf16x8*)&Bs[0][quad][n_l][0];
      bl[i] = *(const bf16x8*)&Bs[1][quad][n_l][0];
    }
#pragma unroll
    for (int i = 0; i < 4; ++i)
#pragma unroll
      for (int j = 0; j < 4; ++j) {
        acc[i][j] = __builtin_amdgcn_mfma_f32_16x16x32_bf16(ah[i], bh[j], acc[i][j], 0, 0, 0);
        acc[i][j] = __builtin_amdgcn_mfma_f32_16x16x32_bf16(ah[i], bl[j], acc[i][j], 0, 0, 0);
        acc[i][j] = __builtin_amdgcn_mfma_f32_16x16x32_bf16(al[i], bh[j], acc[i][j], 0, 0, 0);
      }
    __syncthreads();
  }
#pragma unroll
  for (int i = 0; i < 4; ++i)
#pragma unroll
    for (int j = 0; j < 4; ++j)
#pragma unroll
      for (int r = 0; r < 4; ++r) {
        int m_g = m0 + wm * 64 + i * 16 + quad * 4 + r;
        int n_g = n0 + wn * 64 + j * 16 + l15;
        float v = alpha * acc[i][j][r];
        if (BIASROW) v += bias[m_g];
        if (RELU) v = fmaxf(v, 0.f);
        if (OUTF32) {
          float* C = (float*)Cv + (size_t)bz * sC;
          C[(size_t)m_g * ldc + n_g] = v;
        } else {
          unsigned short* C = (unsigned short*)Cv + (size_t)bz * sC;
          unsigned short h = f2bf(v);
          C[(size_t)m_g * ldc + n_g] = h;
          C[(size_t)m_g * ldc + n_g + plC] = f2bf(v - bf2f(h));
        }
      }
}

// ---------------- weight pack: W (K x N f32) -> Wt (N x K bf16 hi/lo) ----------------
__global__ __launch_bounds__(256) void wpack_k(const float* __restrict__ W, unsigned short* __restrict__ Wt,
                                               int K, int N, long long plane) {
  __shared__ float t[64][65];
  int k0 = blockIdx.x * 64, n0 = blockIdx.y * 64;
  for (int idx = threadIdx.x; idx < 4096; idx += 256) {
    int r = idx >> 6, c = idx & 63;
    t[r][c] = W[(size_t)(k0 + r) * N + n0 + c];
  }
  __syncthreads();
  for (int idx = threadIdx.x; idx < 4096; idx += 256) {
    int r = idx >> 6, c = idx & 63;
    float v = t[c][r];
    unsigned short h = f2bf(v);
    size_t off = (size_t)(n0 + r) * K + k0 + c;
    Wt[off] = h;
    Wt[off + plane] = f2bf(v - bf2f(h));
  }
}

// ---------------- std vectors ----------------
__global__ void sds_k(const float* __restrict__ covx, const float* __restrict__ covr,
                      float* __restrict__ sdx, float* __restrict__ sdr) {
  int idx = blockIdx.x * 256 + threadIdx.x;
  int b = idx >> 9, i = idx & (CN - 1);
  size_t off = (size_t)b * PB + (size_t)i * (CN + 1);
  sdx[idx] = sqrtf(fmaxf(covx[off], EPSF));
  sdr[idx] = sqrtf(fmaxf(covr[off], EPSF));
}

__global__ __launch_bounds__(256) void prep_k(float* __restrict__ covx, float* __restrict__ covr,
                                              const float* __restrict__ sdx, const float* __restrict__ sdr,
                                              float* __restrict__ Lm, float* __restrict__ Wtri) {
  int b = blockIdx.y;
  int e = blockIdx.x * 256 + threadIdx.x;
  int i = e >> 9, j = e & (CN - 1);
  size_t off = (size_t)b * PB + e;
  float cx = covx[off], cr = covr[off];
  Lm[off] = cx + ((i == j) ? 0.001f : 0.0f);
  Wtri[off] = 0.f;
  if (i == j) {
    covx[off] = 1.0f; covr[off] = 1.0f;
  } else {
    covx[off] = cx / (sdx[b * CN + i] * sdx[b * CN + j]);
    covr[off] = cr / (sdr[b * CN + i] * sdr[b * CN + j]);
  }
}

// ---------------- single-wave LDL Cholesky + inverse, fully unrolled inner loops ----------------
// Same math as the verified r12/r13 kernels; inner loops unrolled with compile-time l
// and runtime predicates so the independent LDS ops pipeline instead of serializing.
__global__ __launch_bounds__(64) void chol_diag(const float* __restrict__ A, float* __restrict__ Winv8, int kstep) {
  int b = blockIdx.x;
  const float* Ab = A + (size_t)b * PB + (size_t)(kstep * 64) * CN + kstep * 64;
  const int lane = threadIdx.x;
  __shared__ float Ds[64][65];
  __shared__ float Vs[64][65];
  for (int j = 0; j < 64; ++j) {
    Ds[j][lane] = Ab[(size_t)j * CN + lane];   // coalesced global row read
    Vs[j][lane] = (j == lane) ? 1.f : 0.f;
  }
  __syncthreads();
  // phase A: elimination (unscaled columns). lane = row.
  for (int i = 0; i < 64; ++i) {
    float dinv = 1.0f / Ds[i][i];              // broadcast
    float f = Ds[lane][i] * dinv;              // column, conflict-free
#pragma unroll
    for (int l = 0; l < 64; ++l) {
      if (l > i && l <= lane)
        Ds[lane][l] = fmaf(-f, Ds[l][i], Ds[lane][l]);   // broadcast read + column RMW, pipelined
    }
    __syncthreads();
  }
  // phase B: V = M^{-1} (unit lower). lane = row.
  for (int i = 0; i < 64; ++i) {
    float dinv = 1.0f / Ds[i][i];
    float f = Ds[lane][i] * dinv;
    bool act = (lane > i);
#pragma unroll
    for (int l = 0; l < 64; ++l) {
      if (act && l <= i)
        Vs[lane][l] = fmaf(-f, Vs[i][l], Vs[lane][l]);
    }
    __syncthreads();
  }
  // store: W[r][l] = V[r][l]/sqrt(d_r) on lower triangle; lane = column (coalesced)
  float* Wb = Winv8 + (size_t)b * 32768 + (size_t)kstep * 4096;
  for (int r = 0; r < 64; ++r) {
    float w = (lane <= r) ? Vs[r][lane] / sqrtf(Ds[r][r]) : 0.0f;
    Wb[r * 64 + lane] = w;
  }
}

__global__ void wdiag_k(const float* __restrict__ Winv8, float* __restrict__ W) {
  int e = blockIdx.x * 256 + threadIdx.x;
  int b = e >> 15;
  int r = e & 32767;
  int blk = r >> 12;
  int idx = r & 4095;
  int row = idx >> 6, col = idx & 63;
  W[(size_t)b * PB + (size_t)(blk * 64 + row) * CN + blk * 64 + col] = Winv8[e];
}

__global__ void sdp_k(const float* __restrict__ prec, float* __restrict__ sdp) {
  int idx = blockIdx.x * 256 + threadIdx.x;
  int b = idx >> 9, i = idx & (CN - 1);
  sdp[idx] = sqrtf(fmaxf(prec[(size_t)b * PB + (size_t)i * (CN + 1)], EPSF));
}

__global__ __launch_bounds__(256) void pc_k(float* __restrict__ prec, const float* __restrict__ sdp) {
  int b = blockIdx.y;
  int e = blockIdx.x * 256 + threadIdx.x;
  int i = e >> 9, j = e & (CN - 1);
  size_t off = (size_t)b * PB + e;
  float arg = (i == j) ? 1.0f : -prec[off] / (sdp[b * CN + i] * sdp[b * CN + j]);
  prec[off] = tanhf(arg);
}

// ---------------- similarity sums over strict upper triangle ----------------
__global__ __launch_bounds__(256) void fuse_sums(const float* __restrict__ Pm, const float* __restrict__ Sm,
                                                 const float* __restrict__ Cm, float* __restrict__ sums) {
  int b = blockIdx.y;
  int base = blockIdx.x * 2048;
  float pp = 0, ss = 0, cc = 0, ps = 0, pc = 0, sc = 0;
  for (int u = 0; u < 8; ++u) {
    int e = base + u * 256 + threadIdx.x;
    int i = e >> 9, j = e & (CN - 1);
    if (j > i) {
      size_t off = (size_t)b * PB + e;
      float p = Pm[off];
      float s = Sm[off];
      float cv = Cm[off];
      pp += p * p; ss += s * s; cc += cv * cv;
      ps += p * s; pc += p * cv; sc += s * cv;
    }
  }
  __shared__ float red[256];
  float vals[6] = {pp, ss, cc, ps, pc, sc};
#pragma unroll
  for (int v = 0; v < 6; ++v) {
    red[threadIdx.x] = vals[v];
    __syncthreads();
    for (int s2 = 128; s2 > 0; s2 >>= 1) {
      if (threadIdx.x < s2) red[threadIdx.x] += red[threadIdx.x + s2];
      __syncthreads();
    }
    if (threadIdx.x == 0) atomicAdd(&sums[b * 6 + v], red[0]);
    __syncthreads();
  }
}

__global__ void alphas_k(const float* __restrict__ sums, const float* __restrict__ gamma,
                         float* __restrict__ alph) {
  int b = threadIdx.x;
  if (b >= CB) return;
  float sPP = sums[b * 6 + 0], sSS = sums[b * 6 + 1], sCC = sums[b * 6 + 2];
  float sPS = sums[b * 6 + 3], sPC = sums[b * 6 + 4], sSC = sums[b * 6 + 5];
  float numP = 0.5f * (sPS + sPC), numS = 0.5f * (sPS + sSC), numC = 0.5f * (sPC + sSC);
  float noP = 0.5f * sqrtf(sSS + sCC + 2.f * sSC);
  float noS = 0.5f * sqrtf(sPP + sCC + 2.f * sPC);
  float noC = 0.5f * sqrtf(sPP + sSS + 2.f * sPS);
  float dP = fmaxf(sqrtf(sPP), EPSF) * fmaxf(noP, EPSF);
  float dS = fmaxf(sqrtf(sSS), EPSF) * fmaxf(noS, EPSF);
  float dC = fmaxf(sqrtf(sCC), EPSF) * fmaxf(noC, EPSF);
  float g = gamma[0];
  float aP = g * numP / dP, aS = g * numS / dS, aC = g * numC / dC;
  float m = fmaxf(fmaxf(aP, aS), aC);
  float eP = expf(aP - m), eS = expf(aS - m), eC = expf(aC - m);
  float inv = 1.f / (eP + eS + eC);
  alph[b * 3 + 0] = eP * inv;
  alph[b * 3 + 1] = eS * inv;
  alph[b * 3 + 2] = eC * inv;
}

// ---------------- A_fused row + rowsum fused (f32 out to scratch) ----------------
__global__ __launch_bounds__(256) void bfrow_k(const float* __restrict__ Pm, const float* __restrict__ Sm,
                                               const float* __restrict__ Cm, const float* __restrict__ alph,
                                               float* __restrict__ Af, float* __restrict__ dinv) {
  int b = blockIdx.y, i = blockIdx.x;
  float aP = alph[b * 3 + 0], aS = alph[b * 3 + 1], aC = alph[b * 3 + 2];
  size_t base = (size_t)b * PB + (size_t)i * CN;
  float vsum = 0.f;
#pragma unroll
  for (int h = 0; h < 2; ++h) {
    int j = h * 256 + threadIdx.x;
    float v = (i == j) ? 1.0f
                       : aP * Pm[base + j] + aS * Sm[base + j] + aC * Cm[base + j];
    Af[base + j] = v;
    vsum += v;
  }
  __shared__ float red[256];
  red[threadIdx.x] = vsum;
  __syncthreads();
  for (int s = 128; s > 0; s >>= 1) {
    if (threadIdx.x < s) red[threadIdx.x] += red[threadIdx.x + s];
    __syncthreads();
  }
  if (threadIdx.x == 0) dinv[b * CN + i] = 1.0f / sqrtf(fmaxf(red[0], EPSF));
}

// normalize + pack to bf16 hi/lo planes
__global__ __launch_bounds__(256) void norm_adj_k(const float* __restrict__ AfF, const float* __restrict__ dinv,
                                                  unsigned short* __restrict__ Afp) {
  int b = blockIdx.y;
  int e = blockIdx.x * 256 + threadIdx.x;
  int i = e >> 9, j = e & (CN - 1);
  size_t off = (size_t)b * PB + e;
  float v = AfF[off] * dinv[b * CN + i] * dinv[b * CN + j];
  unsigned short h = f2bf(v);
  Afp[off] = h;
  Afp[off + SBNN] = f2bf(v - bf2f(h));
}

// ---------------- X features + LayerNorm -> packed bf16 hi/lo ----------------
__global__ __launch_bounds__(256) void xbuild_k(const float* __restrict__ Pm, const float* __restrict__ Sm,
                                                const float* __restrict__ Cm,
                                                const float* __restrict__ lng, const float* __restrict__ lnb,
                                                unsigned short* __restrict__ Xpk) {
  int b = blockIdx.y, n = blockIdx.x;
  __shared__ float vals[CIN];
  __shared__ float rs[256], rq[256];
  const float* rows[3] = {Pm + (size_t)b * PB + (size_t)n * CN,
                          Sm + (size_t)b * PB + (size_t)n * CN,
                          Cm + (size_t)b * PB + (size_t)n * CN};
  float ls = 0.f, lq = 0.f;
#pragma unroll
  for (int k = 0; k < 6; ++k) {
    int pos = k * 256 + threadIdx.x;
    int part = pos >> 9;
    int j = pos & (CN - 1);
    float v = rows[part][j];
    vals[pos] = v;
    ls += v; lq += v * v;
  }
  rs[threadIdx.x] = ls; rq[threadIdx.x] = lq;
  __syncthreads();
  for (int s = 128; s > 0; s >>= 1) {
    if (threadIdx.x < s) { rs[threadIdx.x] += rs[threadIdx.x + s]; rq[threadIdx.x] += rq[threadIdx.x + s]; }
    __syncthreads();
  }
  float mu = rs[0] * (1.0f / CIN);
  float var = rq[0] * (1.0f / CIN) - mu * mu;
  float rstd = 1.0f / sqrtf(var + 1e-5f);
  const size_t XPLANE = (size_t)CB * CN * CIN;
  unsigned short* Xrow = Xpk + ((size_t)b * CN + n) * CIN;
#pragma unroll
  for (int k = 0; k < 6; ++k) {
    int pos = k * 256 + threadIdx.x;
    float o = (vals[pos] - mu) * rstd * lng[pos] + lnb[pos];
    unsigned short h = f2bf(o);
    Xrow[pos] = h;
    Xrow[pos + XPLANE] = f2bf(o - bf2f(h));
  }
}

// ---------------- head ----------------
__global__ __launch_bounds__(256) void gmean_k(const float* __restrict__ H, float* __restrict__ gm) {
  int b = blockIdx.y;
  int d = blockIdx.x * 256 + threadIdx.x;
  const float* Hb = H + (size_t)b * CN * CD + d;
  float s = 0.f;
  for (int n = 0; n < CN; ++n) s += Hb[(size_t)n * CD];
  gm[b * CD + d] = s * (1.0f / CN);
}

__global__ __launch_bounds__(256) void final_k(const float* __restrict__ gm, const float* __restrict__ Wc,
                                               const float* __restrict__ bc, float* __restrict__ out) {
  int b = blockIdx.x;
  __shared__ float red[256];
  float s = gm[b * CD + threadIdx.x] * Wc[threadIdx.x] +
            gm[b * CD + 256 + threadIdx.x] * Wc[256 + threadIdx.x];
  red[threadIdx.x] = s;
  __syncthreads();
  for (int k = 128; k > 0; k >>= 1) {
    if (threadIdx.x < k) red[threadIdx.x] += red[threadIdx.x + k];
    __syncthreads();
  }
  if (threadIdx.x == 0) {
    float z = red[0] + bc[0];
    out[b] = 1.0f / (1.0f + expf(-z));
  }
}

// ---------------- launcher ----------------
extern "C" void kernel_launch(void* const* d_in, const int* in_sizes, int n_in,
                              void* d_out, int out_size, void* d_ws, size_t ws_size,
                              hipStream_t stream) {
  const float* x    = (const float*)d_in[0];
  const float* gam  = (const float*)d_in[1];
  const float* lng  = (const float*)d_in[2];
  const float* lnb  = (const float*)d_in[3];
  const float* W0   = (const float*)d_in[4];
  const float* b0   = (const float*)d_in[5];
  const float* W1   = (const float*)d_in[6];
  const float* b1   = (const float*)d_in[7];
  const float* W2   = (const float*)d_in[8];
  const float* b2   = (const float*)d_in[9];
  const float* Wc   = (const float*)d_in[10];
  const float* bc   = (const float*)d_in[11];
  float* out = (float*)d_out;
  float* ws = (float*)d_ws;

  unsigned short* Xtp = (unsigned short*)ws;
  float* Winv8 = ws;                      // Xtp dead after cov
  float* Ttmp  = ws + 524288;
  float* covx  = ws + 16777216;
  float* covr  = covx + SBNN;
  float* Lm    = covx + 2 * SBNN;
  float* Wtri  = covx + 3 * SBNN;
  float* prY   = covx + 4 * SBNN;
  float* sdx   = covx + 5 * SBNN;
  float* sdr   = sdx + 8192;
  float* sdp   = sdr + 8192;
  float* dinv  = sdp + 8192;
  float* gm    = dinv + 8192;
  float* ms    = gm + 8192;
  float* sums  = ms + 8192;
  float* alph  = sums + 96;

  unsigned short* Xpk  = (unsigned short*)ws;
  unsigned short* Afp  = (unsigned short*)(ws + 12582912);
  float*          AfF  = Lm;
  unsigned short* w0t  = (unsigned short*)Lm;
  unsigned short* w1t  = (unsigned short*)(Lm + 1048576);
  unsigned short* w2t  = (unsigned short*)(Lm + 1572864);
  unsigned short* Zt1  = (unsigned short*)prY;
  unsigned short* Zt2  = (unsigned short*)Wtri;
  unsigned short* Zt3  = (unsigned short*)prY;
  unsigned short* H1p  = (unsigned short*)covx;
  unsigned short* H2p  = (unsigned short*)covr;
  float*          Ha   = covx;

  const float covscale = (float)(1.0 / 1023.00000001);
  const long long sPB = (long long)PB;

  zero_k<<<(8288 + 255) / 256, 256, 0, stream>>>(ms, 8288);
  colmean_k<<<dim3(2, CB, 4), 256, 0, stream>>>(x, ms);
  cpack_k<<<dim3(8, 16, CB), 256, 0, stream>>>(x, ms, Xtp);
  ranks_k<<<dim3(CN / 4, CB), 256, 0, stream>>>(x, Xtp);

  // both covariances via bf16-split MFMA (128x128 tiles, 512 blocks)
  gemm_mfma<true, false, false><<<dim3(4, 4, 32), 256, 0, stream>>>(
      Xtp, Xtp, nullptr, covx, 1024, 1024, 1024, CN,
      524288LL, 524288LL, sPB, PLX, PLX, 0LL, covscale);
  sds_k<<<32, 256, 0, stream>>>(covx, covr, sdx, sdr);
  prep_k<<<dim3(1024, CB), 256, 0, stream>>>(covx, covr, sdx, sdr, Lm, Wtri);

  // blocked Cholesky (NB=64), single-wave unrolled diag kernels
  for (int k = 0; k < 8; ++k) {
    chol_diag<<<CB, 64, 0, stream>>>(Lm, Winv8, k);
    int Mt = CN - 64 * (k + 1);
    if (Mt > 0) {
      float* Apan = Lm + (size_t)(k + 1) * 64 * CN + k * 64;
      float* Atrl = Lm + (size_t)(k + 1) * 64 * CN + (k + 1) * 64;
      gemm_k<false, true, false, false><<<dim3(1, Mt / 64, CB), 256, 0, stream>>>(
          Apan, Winv8 + (size_t)k * 4096, nullptr, Apan, Mt, 64, 64, CN, 64, CN,
          sPB, 32768LL, sPB, 1.0f, 1, 0, 0, 0);
      gemm_k<false, true, true, false><<<dim3(Mt / 64, Mt / 64, CB), 256, 0, stream>>>(
          Apan, Apan, nullptr, Atrl, Mt, Mt, 64, CN, CN, CN,
          sPB, sPB, sPB, -1.0f, 1, 0, 0, 0);
    }
  }

  // W = L^{-1}: diag blocks + divide-and-conquer merges
  wdiag_k<<<2048, 256, 0, stream>>>(Winv8, Wtri);
  gemm_k<false, false, false, false><<<dim3(1, 1, CB * 4), 256, 0, stream>>>(
      Lm + 64 * CN, Wtri, nullptr, Ttmp, 64, 64, 64, CN, CN, 64,
      sPB, sPB, 16384LL, 1.0f, 4, 65664LL, 65664LL, 4096LL);
  gemm_k<false, false, false, false><<<dim3(1, 1, CB * 4), 256, 0, stream>>>(
      Wtri + 64 * CN + 64, Ttmp, nullptr, Wtri + 64 * CN, 64, 64, 64, CN, 64, CN,
      sPB, 16384LL, sPB, -1.0f, 4, 65664LL, 4096LL, 65664LL);
  gemm_k<false, false, false, false><<<dim3(2, 2, CB * 2), 256, 0, stream>>>(
      Lm + 128 * CN, Wtri, nullptr, Ttmp, 128, 128, 128, CN, CN, 128,
      sPB, sPB, 32768LL, 1.0f, 2, 131328LL, 131328LL, 16384LL);
  gemm_k<false, false, false, false><<<dim3(2, 2, CB * 2), 256, 0, stream>>>(
      Wtri + 128 * CN + 128, Ttmp, nullptr, Wtri + 128 * CN, 128, 128, 128, CN, 128, CN,
      sPB, 32768LL, sPB, -1.0f, 2, 131328LL, 16384LL, 131328LL);
  gemm_k<false, false, false, false><<<dim3(4, 4, CB), 256, 0, stream>>>(
      Lm + 256 * CN, Wtri, nullptr, Ttmp, 256, 256, 256, CN, CN, 256,
      sPB, sPB, 65536LL, 1.0f, 1, 0, 0, 0);
  gemm_k<false, false, false, false><<<dim3(4, 4, CB), 256, 0, stream>>>(
      Wtri + 256 * CN + 256, Ttmp, nullptr, Wtri + 256 * CN, 256, 256, 256, CN, 256, CN,
      sPB, 65536LL, sPB, -1.0f, 1, 0, 0, 0);

  // prec = W^T W (SYRK)
  gemm_k<true, false, false, false, true><<<dim3(8, 8, CB), 256, 0, stream>>>(
      Wtri, Wtri, nullptr, prY, CN, CN, CN, CN, CN, CN, sPB, sPB, sPB, 1.0f, 1, 0, 0, 0);
  sdp_k<<<32, 256, 0, stream>>>(prY, sdp);
  pc_k<<<dim3(1024, CB), 256, 0, stream>>>(prY, sdp);

  fuse_sums<<<dim3(128, CB), 256, 0, stream>>>(covx, covr, prY, sums);
  alphas_k<<<1, 64, 0, stream>>>(sums, gam, alph);
  bfrow_k<<<dim3(CN, CB), 256, 0, stream>>>(covx, covr, prY, alph, AfF, dinv);
  norm_adj_k<<<dim3(1024, CB), 256, 0, stream>>>(AfF, dinv, Afp);
  xbuild_k<<<dim3(CN, CB), 256, 0, stream>>>(covx, covr, prY, lng, lnb, Xpk);

  wpack_k<<<dim3(24, 8), 256, 0, stream>>>(W0, w0t, CIN, CD, 786432LL);
  wpack_k<<<dim3(8, 8), 256, 0, stream>>>(W1, w1t, CD, CD, 262144LL);
  wpack_k<<<dim3(8, 8), 256, 0, stream>>>(W2, w2t, CD, CD, 262144LL);

  // GCN via bf16-split MFMA (128x128 tiles; orientation alternates, no transposes)
  gemm_mfma<false, false, true><<<dim3(64, 4, 1), 256, 0, stream>>>(
      w0t, Xpk, b0, Zt1, CIN, CIN, CIN, 8192, 0, 0, 0, 786432LL, 12582912LL, 4194304LL, 1.0f);
  gemm_mfma<false, true, false><<<dim3(4, 4, CB), 256, 0, stream>>>(
      Afp, Zt1, nullptr, H1p, CN, CN, 8192, CD, 262144LL, 512LL, 262144LL,
      4194304LL, 4194304LL, 4194304LL, 1.0f);
  gemm_mfma<false, false, true><<<dim3(64, 4, 1), 256, 0, stream>>>(
      w1t, H1p, b1, Zt2, CD, CD, CD, 8192, 0, 0, 0, 262144LL, 4194304LL, 4194304LL, 1.0f);
  gemm_mfma<false, true, false><<<dim3(4, 4, CB), 256, 0, stream>>>(
      Afp, Zt2, nullptr, H2p, CN, CN, 8192, CD, 262144LL, 512LL, 262144LL,
      4194304LL, 4194304LL, 4194304LL, 1.0f);
  gemm_mfma<false, false, true><<<dim3(64, 4, 1), 256, 0, stream>>>(
      w2t, H2p, b2, Zt3, CD, CD, CD, 8192, 0, 0, 0, 262144LL, 4194304LL, 4194304LL, 1.0f);
  gemm_mfma<true, true, false><<<dim3(4, 4, CB), 256, 0, stream>>>(
      Afp, Zt3, nullptr, Ha, CN, CN, 8192, CD, 262144LL, 512LL, 262144LL,
      4194304LL, 4194304LL, 0LL, 1.0f);

  gmean_k<<<dim3(2, CB), 256, 0, stream>>>(Ha, gm);
  final_k<<<CB, 256, 0, stream>>>(gm, Wc, bc, out);
}

// Round 15
// 1862.198 us; speedup vs baseline: 1.8536x; 1.8536x over previous
//
#include <hip/hip_runtime.h>
#include <math.h>

#define EPSF 1e-8f

constexpr int CB = 16;      // batch
constexpr int CT = 1024;    // time
constexpr int CN = 512;     // nodes
constexpr int CD = 512;     // hidden
constexpr int CIN = 1536;   // 3*N
constexpr int PB = CN * CN;
constexpr size_t SBTN = (size_t)CB * CT * CN;
constexpr size_t SBNN = (size_t)CB * PB;
constexpr long long PLX = 16777216LL;   // Xtp plane stride (u16 elems)

typedef __attribute__((ext_vector_type(8))) short bf16x8;
typedef __attribute__((ext_vector_type(4))) float f32x4;

__device__ inline unsigned short f2bf(float x) {   // RNE to bf16
  unsigned u = __float_as_uint(x);
  unsigned r = (u + 0x7fffu + ((u >> 16) & 1u)) >> 16;
  return (unsigned short)r;
}
__device__ inline float bf2f(unsigned short h) { return __uint_as_float(((unsigned)h) << 16); }

// ---------------- utility ----------------
__global__ void zero_k(float* p, int n) {
  int i = blockIdx.x * 256 + threadIdx.x;
  if (i < n) p[i] = 0.f;
}

// ---------------- column means ----------------
__global__ __launch_bounds__(256) void colmean_k(const float* __restrict__ x, float* __restrict__ ms) {
  int b = blockIdx.y;
  int n = blockIdx.x * 256 + threadIdx.x;
  int t0 = blockIdx.z * 256;
  const float* xb = x + (size_t)b * CT * CN + (size_t)t0 * CN + n;
  float s = 0.f;
  for (int t = 0; t < 256; ++t) s += xb[(size_t)t * CN];
  atomicAdd(&ms[b * CN + n], s);
}

// ---------------- centered transpose-pack: x (b,t,n) -> Xtp slot b (n,t) bf16 hi/lo ----------------
__global__ __launch_bounds__(256) void cpack_k(const float* __restrict__ x, const float* __restrict__ ms,
                                               unsigned short* __restrict__ Xtp) {
  __shared__ float t[64][65];
  int b = blockIdx.z, n0 = blockIdx.x * 64, t0 = blockIdx.y * 64;
  const float* xb = x + (size_t)b * CT * CN;
  for (int idx = threadIdx.x; idx < 4096; idx += 256) {
    int r = idx >> 6, c = idx & 63;
    t[r][c] = xb[(size_t)(t0 + r) * CN + n0 + c] - ms[b * CN + n0 + c] * (1.0f / CT);
  }
  __syncthreads();
  unsigned short* base = Xtp + (size_t)b * 524288;
  for (int idx = threadIdx.x; idx < 2048; idx += 256) {
    int nr = idx >> 5, tc = (idx & 31) * 2;
    float v0 = t[tc][nr], v1 = t[tc + 1][nr];
    unsigned short h0 = f2bf(v0), h1 = f2bf(v1);
    unsigned short l0 = f2bf(v0 - bf2f(h0)), l1 = f2bf(v1 - bf2f(h1));
    size_t off = (size_t)(n0 + nr) * 1024 + t0 + tc;
    *(unsigned int*)&base[off] = (unsigned int)h0 | ((unsigned int)h1 << 16);
    *(unsigned int*)&base[off + PLX] = (unsigned int)l0 | ((unsigned int)l1 << 16);
  }
}

// ---------------- Spearman ranks: merge-split bitonic (run-granularity) ----------------
static __device__ inline unsigned long long shflx64(unsigned long long v, int m) {
  int lo = __shfl_xor((int)(unsigned)v, m, 64);
  int hi = __shfl_xor((int)(unsigned)(v >> 32), m, 64);
  return ((unsigned long long)(unsigned)hi << 32) | (unsigned)lo;
}

__global__ __launch_bounds__(256) void ranks_k(const float* __restrict__ x, unsigned short* __restrict__ Xtp) {
  int b = blockIdx.y;
  int n0 = blockIdx.x * 4;
  __shared__ float stage[4][1032];
  const float* xb = x + (size_t)b * CT * CN + n0;
  for (int t = threadIdx.x; t < 1024; t += 256) {
    float4 v = *(const float4*)&xb[(size_t)t * CN];
    stage[0][t] = v.x; stage[1][t] = v.y; stage[2][t] = v.z; stage[3][t] = v.w;
  }
  __syncthreads();
  const int c = threadIdx.x >> 6;
  const int lane = threadIdx.x & 63;
  unsigned long long kv[16];
#pragma unroll
  for (int m = 0; m < 16; ++m) {
    int pos = m * 64 + lane;
    unsigned int u = __float_as_uint(stage[c][pos]);
    u = (u & 0x80000000u) ? ~u : (u | 0x80000000u);
    kv[m] = (((unsigned long long)u) << 32) | (unsigned)pos;
  }
#define CE_KV(a, bb, up) { bool sw_ = (up) ? (kv[a] > kv[bb]) : (kv[a] < kv[bb]); \
  if (sw_) { unsigned long long t_ = kv[a]; kv[a] = kv[bb]; kv[bb] = t_; } }
  // phase 1: in-lane bitonic sort of 16 (ascending), pure VALU
#pragma unroll
  for (int k2 = 2; k2 <= 16; k2 <<= 1) {
#pragma unroll
    for (int j2 = 8; j2 >= 1; j2 >>= 1) {
      if (j2 >= k2) continue;
#pragma unroll
      for (int t = 0; t < 16; ++t)
        if (!(t & j2)) { bool up2 = ((t & k2) == 0); CE_KV(t, t | j2, up2); }
    }
  }
  // phase 2: bitonic network over 64 sorted runs; CE = merge-split
#pragma unroll
  for (int k = 2; k <= 64; k <<= 1) {
#pragma unroll
    for (int j = 32; j >= 1; j >>= 1) {
      if (j >= k) continue;
      bool up = ((lane & k) == 0);
      bool isLow = ((lane & j) == 0);
      bool keepMin = (isLow == up);
      unsigned long long oth[16];
#pragma unroll
      for (int i = 0; i < 16; ++i) oth[i] = shflx64(kv[15 - i], j);
#pragma unroll
      for (int i = 0; i < 16; ++i) {
        unsigned long long o = oth[i];
        bool less = kv[i] < o;
        kv[i] = (less == keepMin) ? kv[i] : o;
      }
#pragma unroll
      for (int j2 = 8; j2 >= 1; j2 >>= 1)
#pragma unroll
        for (int t = 0; t < 16; ++t)
          if (!(t & j2)) CE_KV(t, t | j2, true);
    }
  }
#undef CE_KV
#pragma unroll
  for (int m = 0; m < 16; ++m) {
    unsigned int pos = (unsigned int)kv[m] & 1023u;
    stage[c][pos] = ((float)(lane * 16 + m + 1) - 512.5f) * (1.0f / 512.0f);
  }
  __syncthreads();
  unsigned short* base = Xtp + (size_t)(16 + b) * 524288;
  for (int idx = threadIdx.x; idx < 2048; idx += 256) {
    int row = idx >> 9, t2 = (idx & 511) * 2;
    float v0 = stage[row][t2], v1 = stage[row][t2 + 1];
    unsigned short h0 = f2bf(v0), h1 = f2bf(v1);
    unsigned short l0 = f2bf(v0 - bf2f(h0)), l1 = f2bf(v1 - bf2f(h1));
    size_t off = (size_t)(n0 + row) * 1024 + t2;
    *(unsigned int*)&base[off] = (unsigned int)h0 | ((unsigned int)h1 << 16);
    *(unsigned int*)&base[off + PLX] = (unsigned int)l0 | ((unsigned int)l1 << 16);
  }
}

// ---------------- generic fp32 tiled GEMM (64x64 tile) + pair batching ----------------
template<bool TA, bool TB, bool ACC, bool RELU, bool SYRK = false>
__global__ __launch_bounds__(256) void gemm_k(
    const float* __restrict__ A, const float* __restrict__ B,
    const float* __restrict__ bias, float* __restrict__ C,
    int M, int Nc, int K, int lda, int ldb, int ldc,
    long long sA, long long sB, long long sC, float alpha,
    int pairs, long long pA, long long pB, long long pC) {
  __shared__ float As[16][68];
  __shared__ float Bs[16][68];
  const int bz = blockIdx.z;
  const int b = bz / pairs;
  const int p = bz - b * pairs;
  A += (size_t)b * sA + (size_t)p * pA;
  B += (size_t)b * sB + (size_t)p * pB;
  C += (size_t)b * sC + (size_t)p * pC;
  const int n0 = blockIdx.x * 64;
  const int m0 = blockIdx.y * 64;
  const int tid = threadIdx.x;
  const int tn = (tid & 15) * 4;
  const int tm = (tid >> 4) * 4;
  float acc[4][4];
#pragma unroll
  for (int i = 0; i < 4; ++i)
#pragma unroll
    for (int j = 0; j < 4; ++j) acc[i][j] = 0.f;

  const int kbeg = SYRK ? (m0 > n0 ? m0 : n0) : 0;
  for (int k0 = kbeg; k0 < K; k0 += 16) {
    if (TA) {
      const int lk = tid >> 4;
      const int lm = (tid & 15) * 4;
      const float4 v = *(const float4*)&A[(size_t)(k0 + lk) * lda + m0 + lm];
      *(float4*)&As[lk][lm] = v;
    } else {
      const int lm = tid >> 2;
      const int lk = (tid & 3) * 4;
      const float4 v = *(const float4*)&A[(size_t)(m0 + lm) * lda + k0 + lk];
      As[lk + 0][lm] = v.x; As[lk + 1][lm] = v.y; As[lk + 2][lm] = v.z; As[lk + 3][lm] = v.w;
    }
    if (TB) {
      const int ln = tid >> 2;
      const int lk = (tid & 3) * 4;
      const float4 v = *(const float4*)&B[(size_t)(n0 + ln) * ldb + k0 + lk];
      Bs[lk + 0][ln] = v.x; Bs[lk + 1][ln] = v.y; Bs[lk + 2][ln] = v.z; Bs[lk + 3][ln] = v.w;
    } else {
      const int lk = tid >> 4;
      const int ln = (tid & 15) * 4;
      const float4 v = *(const float4*)&B[(size_t)(k0 + lk) * ldb + n0 + ln];
      *(float4*)&Bs[lk][ln] = v;
    }
    __syncthreads();
#pragma unroll
    for (int kk = 0; kk < 16; ++kk) {
      const float4 a4 = *(const float4*)&As[kk][tm];
      const float4 b4 = *(const float4*)&Bs[kk][tn];
      const float av[4] = {a4.x, a4.y, a4.z, a4.w};
      const float bv[4] = {b4.x, b4.y, b4.z, b4.w};
#pragma unroll
      for (int i = 0; i < 4; ++i)
#pragma unroll
        for (int j = 0; j < 4; ++j) acc[i][j] = fmaf(av[i], bv[j], acc[i][j]);
    }
    __syncthreads();
  }
  float4 bb = make_float4(0.f, 0.f, 0.f, 0.f);
  if (bias) bb = *(const float4*)&bias[n0 + tn];
#pragma unroll
  for (int i = 0; i < 4; ++i) {
    size_t off = (size_t)(m0 + tm + i) * ldc + (n0 + tn);
    float4 v;
    v.x = alpha * acc[i][0] + bb.x;
    v.y = alpha * acc[i][1] + bb.y;
    v.z = alpha * acc[i][2] + bb.z;
    v.w = alpha * acc[i][3] + bb.w;
    if (ACC) {
      const float4 c0 = *(const float4*)&C[off];
      v.x += c0.x; v.y += c0.y; v.z += c0.z; v.w += c0.w;
    }
    if (RELU) {
      v.x = fmaxf(v.x, 0.f); v.y = fmaxf(v.y, 0.f);
      v.z = fmaxf(v.z, 0.f); v.w = fmaxf(v.w, 0.f);
    }
    *(float4*)&C[off] = v;
  }
}

// ---------------- bf16-split MFMA GEMM (128M x 128N tile, wave 64x64, K-step 32) ----------------
template<bool OUTF32, bool RELU, bool BIASROW>
__global__ __launch_bounds__(256, 2) void gemm_mfma(
    const unsigned short* __restrict__ A, const unsigned short* __restrict__ B,
    const float* __restrict__ bias, void* __restrict__ Cv,
    int K, int lda, int ldb, int ldc,
    long long sA, long long sB, long long sC,
    long long plA, long long plB, long long plC, float alpha) {
  __shared__ unsigned short As[2][4][128][8];
  __shared__ unsigned short Bs[2][4][128][8];
  const int bz = blockIdx.z;
  A += (size_t)bz * sA;
  B += (size_t)bz * sB;
  const int n0 = blockIdx.x * 128;
  const int m0 = blockIdx.y * 128;
  const int tid = threadIdx.x;
  const int wave = tid >> 6, lane = tid & 63;
  const int wm = wave & 1, wn = wave >> 1;
  const int l15 = lane & 15, quad = lane >> 4;
  const int r2 = tid >> 1;
  const int sp = (tid & 1) * 2;
  f32x4 acc[4][4];
#pragma unroll
  for (int i = 0; i < 4; ++i)
#pragma unroll
    for (int j = 0; j < 4; ++j) acc[i][j] = (f32x4){0.f, 0.f, 0.f, 0.f};

  for (int k0 = 0; k0 < K; k0 += 32) {
    const unsigned short* sa = A + (size_t)(m0 + r2) * lda + k0 + sp * 8;
    const unsigned short* sb = B + (size_t)(n0 + r2) * ldb + k0 + sp * 8;
    *(bf16x8*)&As[0][sp][r2][0]     = *(const bf16x8*)sa;
    *(bf16x8*)&As[0][sp + 1][r2][0] = *(const bf16x8*)(sa + 8);
    *(bf16x8*)&As[1][sp][r2][0]     = *(const bf16x8*)(sa + plA);
    *(bf16x8*)&As[1][sp + 1][r2][0] = *(const bf16x8*)(sa + plA + 8);
    *(bf16x8*)&Bs[0][sp][r2][0]     = *(const bf16x8*)sb;
    *(bf16x8*)&Bs[0][sp + 1][r2][0] = *(const bf16x8*)(sb + 8);
    *(bf16x8*)&Bs[1][sp][r2][0]     = *(const bf16x8*)(sb + plB);
    *(bf16x8*)&Bs[1][sp + 1][r2][0] = *(const bf16x8*)(sb + plB + 8);
    __syncthreads();
    bf16x8 ah[4], al[4], bh[4], bl[4];
#pragma unroll
    for (int i = 0; i < 4; ++i) {
      int m_l = wm * 64 + i * 16 + l15;
      int n_l = wn * 64 + i * 16 + l15;
      ah[i] = *(const bf16x8*)&As[0][quad][m_l][0];
      al[i] = *(const bf16x8*)&As[1][quad][m_l][0];
      bh[i] = *(const bf16x8*)&Bs[0][quad][n_l][0];
      bl[i] = *(const bf16x8*)&Bs[1][quad][n_l][0];
    }
#pragma unroll
    for (int i = 0; i < 4; ++i)
#pragma unroll
      for (int j = 0; j < 4; ++j) {
        acc[i][j] = __builtin_amdgcn_mfma_f32_16x16x32_bf16(ah[i], bh[j], acc[i][j], 0, 0, 0);
        acc[i][j] = __builtin_amdgcn_mfma_f32_16x16x32_bf16(ah[i], bl[j], acc[i][j], 0, 0, 0);
        acc[i][j] = __builtin_amdgcn_mfma_f32_16x16x32_bf16(al[i], bh[j], acc[i][j], 0, 0, 0);
      }
    __syncthreads();
  }
#pragma unroll
  for (int i = 0; i < 4; ++i)
#pragma unroll
    for (int j = 0; j < 4; ++j)
#pragma unroll
      for (int r = 0; r < 4; ++r) {
        int m_g = m0 + wm * 64 + i * 16 + quad * 4 + r;
        int n_g = n0 + wn * 64 + j * 16 + l15;
        float v = alpha * acc[i][j][r];
        if (BIASROW) v += bias[m_g];
        if (RELU) v = fmaxf(v, 0.f);
        if (OUTF32) {
          float* C = (float*)Cv + (size_t)bz * sC;
          C[(size_t)m_g * ldc + n_g] = v;
        } else {
          unsigned short* C = (unsigned short*)Cv + (size_t)bz * sC;
          unsigned short h = f2bf(v);
          C[(size_t)m_g * ldc + n_g] = h;
          C[(size_t)m_g * ldc + n_g + plC] = f2bf(v - bf2f(h));
        }
      }
}

// ---------------- weight pack: W (K x N f32) -> Wt (N x K bf16 hi/lo) ----------------
__global__ __launch_bounds__(256) void wpack_k(const float* __restrict__ W, unsigned short* __restrict__ Wt,
                                               int K, int N, long long plane) {
  __shared__ float t[64][65];
  int k0 = blockIdx.x * 64, n0 = blockIdx.y * 64;
  for (int idx = threadIdx.x; idx < 4096; idx += 256) {
    int r = idx >> 6, c = idx & 63;
    t[r][c] = W[(size_t)(k0 + r) * N + n0 + c];
  }
  __syncthreads();
  for (int idx = threadIdx.x; idx < 4096; idx += 256) {
    int r = idx >> 6, c = idx & 63;
    float v = t[c][r];
    unsigned short h = f2bf(v);
    size_t off = (size_t)(n0 + r) * K + k0 + c;
    Wt[off] = h;
    Wt[off + plane] = f2bf(v - bf2f(h));
  }
}

// ---------------- std vectors ----------------
__global__ void sds_k(const float* __restrict__ covx, const float* __restrict__ covr,
                      float* __restrict__ sdx, float* __restrict__ sdr) {
  int idx = blockIdx.x * 256 + threadIdx.x;
  int b = idx >> 9, i = idx & (CN - 1);
  size_t off = (size_t)b * PB + (size_t)i * (CN + 1);
  sdx[idx] = sqrtf(fmaxf(covx[off], EPSF));
  sdr[idx] = sqrtf(fmaxf(covr[off], EPSF));
}

__global__ __launch_bounds__(256) void prep_k(float* __restrict__ covx, float* __restrict__ covr,
                                              const float* __restrict__ sdx, const float* __restrict__ sdr,
                                              float* __restrict__ Lm, float* __restrict__ Wtri) {
  int b = blockIdx.y;
  int e = blockIdx.x * 256 + threadIdx.x;
  int i = e >> 9, j = e & (CN - 1);
  size_t off = (size_t)b * PB + e;
  float cx = covx[off], cr = covr[off];
  Lm[off] = cx + ((i == j) ? 0.001f : 0.0f);
  Wtri[off] = 0.f;
  if (i == j) {
    covx[off] = 1.0f; covr[off] = 1.0f;
  } else {
    covx[off] = cx / (sdx[b * CN + i] * sdx[b * CN + j]);
    covr[off] = cr / (sdr[b * CN + i] * sdr[b * CN + j]);
  }
}

// ---------------- register-tile LDL Cholesky + inverse (no LDS RMW in update path) ----------------
// 256 threads: thread owns row r=tid>>2, col segment s=tid&3 (16 regs, static index).
// Per step: owners publish frozen column i (parity colbuf + archive Lcol), 1 barrier,
// then pure register fmas with broadcast LDS reads. Lower-triangle arithmetic is
// op-for-op identical to the verified r12/r13 kernels (input is bit-symmetric).
__global__ __launch_bounds__(256) void chol_diag(const float* __restrict__ A, float* __restrict__ Winv8, int kstep) {
  int b = blockIdx.x;
  const float* Ab = A + (size_t)b * PB + (size_t)(kstep * 64) * CN + kstep * 64;
  const int tid = threadIdx.x;
  const int r = tid >> 2;
  const int s = tid & 3;
  const int c0 = s * 16;
  __shared__ float colbuf[2][64];
  __shared__ float rowbuf[2][64];
  __shared__ float Lcol[64][65];    // Lcol[i][r] = frozen column i at row r
  float a[16];
#pragma unroll
  for (int q = 0; q < 4; ++q) {
    float4 v = *(const float4*)&Ab[(size_t)r * CN + c0 + q * 4];
    a[q * 4 + 0] = v.x; a[q * 4 + 1] = v.y; a[q * 4 + 2] = v.z; a[q * 4 + 3] = v.w;
  }
  // phase A: elimination with deferred scaling (unscaled columns)
  for (int i = 0; i < 64; ++i) {
    int par = i & 1;
    if (s == (i >> 4)) {
      float asel = a[0];
#pragma unroll
      for (int cc = 1; cc < 16; ++cc)
        if ((i & 15) == cc) asel = a[cc];
      colbuf[par][r] = asel;
      Lcol[i][r] = asel;
    }
    __syncthreads();
    float dinv = 1.0f / colbuf[par][i];
    float f = colbuf[par][r] * dinv;
#pragma unroll
    for (int cc = 0; cc < 16; ++cc) {
      int cgl = c0 + cc;
      float cv = colbuf[par][cgl];
      if (cgl > i) a[cc] = fmaf(-f, cv, a[cc]);
    }
  }
  __syncthreads();
  // phase B: V = M^{-1} (unit lower), rows in registers
  float v[16];
#pragma unroll
  for (int cc = 0; cc < 16; ++cc) v[cc] = (c0 + cc == r) ? 1.0f : 0.0f;
  for (int i = 0; i < 64; ++i) {
    int par = i & 1;
    if (r == i) {
#pragma unroll
      for (int cc = 0; cc < 16; ++cc) rowbuf[par][c0 + cc] = v[cc];
    }
    __syncthreads();
    float dinv = 1.0f / Lcol[i][i];
    float f = Lcol[i][r] * dinv;
    if (r > i) {
#pragma unroll
      for (int cc = 0; cc < 16; ++cc) {
        int cgl = c0 + cc;
        float rv = rowbuf[par][cgl];
        if (cgl <= i) v[cc] = fmaf(-f, rv, v[cc]);
      }
    }
  }
  // store: W[r][l] = V[r][l]/sqrt(d_r) lower, else 0 (coalesced float4)
  float* Wb = Winv8 + (size_t)b * 32768 + (size_t)kstep * 4096;
  float dr = sqrtf(Lcol[r][r]);
#pragma unroll
  for (int q = 0; q < 4; ++q) {
    float4 o;
    float t0v = (c0 + q * 4 + 0 <= r) ? v[q * 4 + 0] / dr : 0.0f;
    float t1v = (c0 + q * 4 + 1 <= r) ? v[q * 4 + 1] / dr : 0.0f;
    float t2v = (c0 + q * 4 + 2 <= r) ? v[q * 4 + 2] / dr : 0.0f;
    float t3v = (c0 + q * 4 + 3 <= r) ? v[q * 4 + 3] / dr : 0.0f;
    o.x = t0v; o.y = t1v; o.z = t2v; o.w = t3v;
    *(float4*)&Wb[r * 64 + c0 + q * 4] = o;
  }
}

__global__ void wdiag_k(const float* __restrict__ Winv8, float* __restrict__ W) {
  int e = blockIdx.x * 256 + threadIdx.x;
  int b = e >> 15;
  int r = e & 32767;
  int blk = r >> 12;
  int idx = r & 4095;
  int row = idx >> 6, col = idx & 63;
  W[(size_t)b * PB + (size_t)(blk * 64 + row) * CN + blk * 64 + col] = Winv8[e];
}

__global__ void sdp_k(const float* __restrict__ prec, float* __restrict__ sdp) {
  int idx = blockIdx.x * 256 + threadIdx.x;
  int b = idx >> 9, i = idx & (CN - 1);
  sdp[idx] = sqrtf(fmaxf(prec[(size_t)b * PB + (size_t)i * (CN + 1)], EPSF));
}

__global__ __launch_bounds__(256) void pc_k(float* __restrict__ prec, const float* __restrict__ sdp) {
  int b = blockIdx.y;
  int e = blockIdx.x * 256 + threadIdx.x;
  int i = e >> 9, j = e & (CN - 1);
  size_t off = (size_t)b * PB + e;
  float arg = (i == j) ? 1.0f : -prec[off] / (sdp[b * CN + i] * sdp[b * CN + j]);
  prec[off] = tanhf(arg);
}

// ---------------- similarity sums over strict upper triangle ----------------
__global__ __launch_bounds__(256) void fuse_sums(const float* __restrict__ Pm, const float* __restrict__ Sm,
                                                 const float* __restrict__ Cm, float* __restrict__ sums) {
  int b = blockIdx.y;
  int base = blockIdx.x * 2048;
  float pp = 0, ss = 0, cc = 0, ps = 0, pc = 0, sc = 0;
  for (int u = 0; u < 8; ++u) {
    int e = base + u * 256 + threadIdx.x;
    int i = e >> 9, j = e & (CN - 1);
    if (j > i) {
      size_t off = (size_t)b * PB + e;
      float p = Pm[off];
      float s = Sm[off];
      float cv = Cm[off];
      pp += p * p; ss += s * s; cc += cv * cv;
      ps += p * s; pc += p * cv; sc += s * cv;
    }
  }
  __shared__ float red[256];
  float vals[6] = {pp, ss, cc, ps, pc, sc};
#pragma unroll
  for (int v = 0; v < 6; ++v) {
    red[threadIdx.x] = vals[v];
    __syncthreads();
    for (int s2 = 128; s2 > 0; s2 >>= 1) {
      if (threadIdx.x < s2) red[threadIdx.x] += red[threadIdx.x + s2];
      __syncthreads();
    }
    if (threadIdx.x == 0) atomicAdd(&sums[b * 6 + v], red[0]);
    __syncthreads();
  }
}

__global__ void alphas_k(const float* __restrict__ sums, const float* __restrict__ gamma,
                         float* __restrict__ alph) {
  int b = threadIdx.x;
  if (b >= CB) return;
  float sPP = sums[b * 6 + 0], sSS = sums[b * 6 + 1], sCC = sums[b * 6 + 2];
  float sPS = sums[b * 6 + 3], sPC = sums[b * 6 + 4], sSC = sums[b * 6 + 5];
  float numP = 0.5f * (sPS + sPC), numS = 0.5f * (sPS + sSC), numC = 0.5f * (sPC + sSC);
  float noP = 0.5f * sqrtf(sSS + sCC + 2.f * sSC);
  float noS = 0.5f * sqrtf(sPP + sCC + 2.f * sPC);
  float noC = 0.5f * sqrtf(sPP + sSS + 2.f * sPS);
  float dP = fmaxf(sqrtf(sPP), EPSF) * fmaxf(noP, EPSF);
  float dS = fmaxf(sqrtf(sSS), EPSF) * fmaxf(noS, EPSF);
  float dC = fmaxf(sqrtf(sCC), EPSF) * fmaxf(noC, EPSF);
  float g = gamma[0];
  float aP = g * numP / dP, aS = g * numS / dS, aC = g * numC / dC;
  float m = fmaxf(fmaxf(aP, aS), aC);
  float eP = expf(aP - m), eS = expf(aS - m), eC = expf(aC - m);
  float inv = 1.f / (eP + eS + eC);
  alph[b * 3 + 0] = eP * inv;
  alph[b * 3 + 1] = eS * inv;
  alph[b * 3 + 2] = eC * inv;
}

// ---------------- A_fused row + rowsum fused (f32 out to scratch) ----------------
__global__ __launch_bounds__(256) void bfrow_k(const float* __restrict__ Pm, const float* __restrict__ Sm,
                                               const float* __restrict__ Cm, const float* __restrict__ alph,
                                               float* __restrict__ Af, float* __restrict__ dinv) {
  int b = blockIdx.y, i = blockIdx.x;
  float aP = alph[b * 3 + 0], aS = alph[b * 3 + 1], aC = alph[b * 3 + 2];
  size_t base = (size_t)b * PB + (size_t)i * CN;
  float vsum = 0.f;
#pragma unroll
  for (int h = 0; h < 2; ++h) {
    int j = h * 256 + threadIdx.x;
    float v = (i == j) ? 1.0f
                       : aP * Pm[base + j] + aS * Sm[base + j] + aC * Cm[base + j];
    Af[base + j] = v;
    vsum += v;
  }
  __shared__ float red[256];
  red[threadIdx.x] = vsum;
  __syncthreads();
  for (int s = 128; s > 0; s >>= 1) {
    if (threadIdx.x < s) red[threadIdx.x] += red[threadIdx.x + s];
    __syncthreads();
  }
  if (threadIdx.x == 0) dinv[b * CN + i] = 1.0f / sqrtf(fmaxf(red[0], EPSF));
}

// normalize + pack to bf16 hi/lo planes
__global__ __launch_bounds__(256) void norm_adj_k(const float* __restrict__ AfF, const float* __restrict__ dinv,
                                                  unsigned short* __restrict__ Afp) {
  int b = blockIdx.y;
  int e = blockIdx.x * 256 + threadIdx.x;
  int i = e >> 9, j = e & (CN - 1);
  size_t off = (size_t)b * PB + e;
  float v = AfF[off] * dinv[b * CN + i] * dinv[b * CN + j];
  unsigned short h = f2bf(v);
  Afp[off] = h;
  Afp[off + SBNN] = f2bf(v - bf2f(h));
}

// ---------------- X features + LayerNorm -> packed bf16 hi/lo ----------------
__global__ __launch_bounds__(256) void xbuild_k(const float* __restrict__ Pm, const float* __restrict__ Sm,
                                                const float* __restrict__ Cm,
                                                const float* __restrict__ lng, const float* __restrict__ lnb,
                                                unsigned short* __restrict__ Xpk) {
  int b = blockIdx.y, n = blockIdx.x;
  __shared__ float vals[CIN];
  __shared__ float rs[256], rq[256];
  const float* rows[3] = {Pm + (size_t)b * PB + (size_t)n * CN,
                          Sm + (size_t)b * PB + (size_t)n * CN,
                          Cm + (size_t)b * PB + (size_t)n * CN};
  float ls = 0.f, lq = 0.f;
#pragma unroll
  for (int k = 0; k < 6; ++k) {
    int pos = k * 256 + threadIdx.x;
    int part = pos >> 9;
    int j = pos & (CN - 1);
    float v = rows[part][j];
    vals[pos] = v;
    ls += v; lq += v * v;
  }
  rs[threadIdx.x] = ls; rq[threadIdx.x] = lq;
  __syncthreads();
  for (int s = 128; s > 0; s >>= 1) {
    if (threadIdx.x < s) { rs[threadIdx.x] += rs[threadIdx.x + s]; rq[threadIdx.x] += rq[threadIdx.x + s]; }
    __syncthreads();
  }
  float mu = rs[0] * (1.0f / CIN);
  float var = rq[0] * (1.0f / CIN) - mu * mu;
  float rstd = 1.0f / sqrtf(var + 1e-5f);
  const size_t XPLANE = (size_t)CB * CN * CIN;
  unsigned short* Xrow = Xpk + ((size_t)b * CN + n) * CIN;
#pragma unroll
  for (int k = 0; k < 6; ++k) {
    int pos = k * 256 + threadIdx.x;
    float o = (vals[pos] - mu) * rstd * lng[pos] + lnb[pos];
    unsigned short h = f2bf(o);
    Xrow[pos] = h;
    Xrow[pos + XPLANE] = f2bf(o - bf2f(h));
  }
}

// ---------------- head ----------------
__global__ __launch_bounds__(256) void gmean_k(const float* __restrict__ H, float* __restrict__ gm) {
  int b = blockIdx.y;
  int d = blockIdx.x * 256 + threadIdx.x;
  const float* Hb = H + (size_t)b * CN * CD + d;
  float s = 0.f;
  for (int n = 0; n < CN; ++n) s += Hb[(size_t)n * CD];
  gm[b * CD + d] = s * (1.0f / CN);
}

__global__ __launch_bounds__(256) void final_k(const float* __restrict__ gm, const float* __restrict__ Wc,
                                               const float* __restrict__ bc, float* __restrict__ out) {
  int b = blockIdx.x;
  __shared__ float red[256];
  float s = gm[b * CD + threadIdx.x] * Wc[threadIdx.x] +
            gm[b * CD + 256 + threadIdx.x] * Wc[256 + threadIdx.x];
  red[threadIdx.x] = s;
  __syncthreads();
  for (int k = 128; k > 0; k >>= 1) {
    if (threadIdx.x < k) red[threadIdx.x] += red[threadIdx.x + k];
    __syncthreads();
  }
  if (threadIdx.x == 0) {
    float z = red[0] + bc[0];
    out[b] = 1.0f / (1.0f + expf(-z));
  }
}

// ---------------- launcher ----------------
extern "C" void kernel_launch(void* const* d_in, const int* in_sizes, int n_in,
                              void* d_out, int out_size, void* d_ws, size_t ws_size,
                              hipStream_t stream) {
  const float* x    = (const float*)d_in[0];
  const float* gam  = (const float*)d_in[1];
  const float* lng  = (const float*)d_in[2];
  const float* lnb  = (const float*)d_in[3];
  const float* W0   = (const float*)d_in[4];
  const float* b0   = (const float*)d_in[5];
  const float* W1   = (const float*)d_in[6];
  const float* b1   = (const float*)d_in[7];
  const float* W2   = (const float*)d_in[8];
  const float* b2   = (const float*)d_in[9];
  const float* Wc   = (const float*)d_in[10];
  const float* bc   = (const float*)d_in[11];
  float* out = (float*)d_out;
  float* ws = (float*)d_ws;

  unsigned short* Xtp = (unsigned short*)ws;
  float* Winv8 = ws;                      // Xtp dead after cov
  float* Ttmp  = ws + 524288;
  float* covx  = ws + 16777216;
  float* covr  = covx + SBNN;
  float* Lm    = covx + 2 * SBNN;
  float* Wtri  = covx + 3 * SBNN;
  float* prY   = covx + 4 * SBNN;
  float* sdx   = covx + 5 * SBNN;
  float* sdr   = sdx + 8192;
  float* sdp   = sdr + 8192;
  float* dinv  = sdp + 8192;
  float* gm    = dinv + 8192;
  float* ms    = gm + 8192;
  float* sums  = ms + 8192;
  float* alph  = sums + 96;

  unsigned short* Xpk  = (unsigned short*)ws;
  unsigned short* Afp  = (unsigned short*)(ws + 12582912);
  float*          AfF  = Lm;
  unsigned short* w0t  = (unsigned short*)Lm;
  unsigned short* w1t  = (unsigned short*)(Lm + 1048576);
  unsigned short* w2t  = (unsigned short*)(Lm + 1572864);
  unsigned short* Zt1  = (unsigned short*)prY;
  unsigned short* Zt2  = (unsigned short*)Wtri;
  unsigned short* Zt3  = (unsigned short*)prY;
  unsigned short* H1p  = (unsigned short*)covx;
  unsigned short* H2p  = (unsigned short*)covr;
  float*          Ha   = covx;

  const float covscale = (float)(1.0 / 1023.00000001);
  const long long sPB = (long long)PB;

  zero_k<<<(8288 + 255) / 256, 256, 0, stream>>>(ms, 8288);
  colmean_k<<<dim3(2, CB, 4), 256, 0, stream>>>(x, ms);
  cpack_k<<<dim3(8, 16, CB), 256, 0, stream>>>(x, ms, Xtp);
  ranks_k<<<dim3(CN / 4, CB), 256, 0, stream>>>(x, Xtp);

  // both covariances via bf16-split MFMA (128x128 tiles, 512 blocks)
  gemm_mfma<true, false, false><<<dim3(4, 4, 32), 256, 0, stream>>>(
      Xtp, Xtp, nullptr, covx, 1024, 1024, 1024, CN,
      524288LL, 524288LL, sPB, PLX, PLX, 0LL, covscale);
  sds_k<<<32, 256, 0, stream>>>(covx, covr, sdx, sdr);
  prep_k<<<dim3(1024, CB), 256, 0, stream>>>(covx, covr, sdx, sdr, Lm, Wtri);

  // blocked Cholesky (NB=64), register-tile diag kernels
  for (int k = 0; k < 8; ++k) {
    chol_diag<<<CB, 256, 0, stream>>>(Lm, Winv8, k);
    int Mt = CN - 64 * (k + 1);
    if (Mt > 0) {
      float* Apan = Lm + (size_t)(k + 1) * 64 * CN + k * 64;
      float* Atrl = Lm + (size_t)(k + 1) * 64 * CN + (k + 1) * 64;
      gemm_k<false, true, false, false><<<dim3(1, Mt / 64, CB), 256, 0, stream>>>(
          Apan, Winv8 + (size_t)k * 4096, nullptr, Apan, Mt, 64, 64, CN, 64, CN,
          sPB, 32768LL, sPB, 1.0f, 1, 0, 0, 0);
      gemm_k<false, true, true, false><<<dim3(Mt / 64, Mt / 64, CB), 256, 0, stream>>>(
          Apan, Apan, nullptr, Atrl, Mt, Mt, 64, CN, CN, CN,
          sPB, sPB, sPB, -1.0f, 1, 0, 0, 0);
    }
  }

  // W = L^{-1}: diag blocks + divide-and-conquer merges
  wdiag_k<<<2048, 256, 0, stream>>>(Winv8, Wtri);
  gemm_k<false, false, false, false><<<dim3(1, 1, CB * 4), 256, 0, stream>>>(
      Lm + 64 * CN, Wtri, nullptr, Ttmp, 64, 64, 64, CN, CN, 64,
      sPB, sPB, 16384LL, 1.0f, 4, 65664LL, 65664LL, 4096LL);
  gemm_k<false, false, false, false><<<dim3(1, 1, CB * 4), 256, 0, stream>>>(
      Wtri + 64 * CN + 64, Ttmp, nullptr, Wtri + 64 * CN, 64, 64, 64, CN, 64, CN,
      sPB, 16384LL, sPB, -1.0f, 4, 65664LL, 4096LL, 65664LL);
  gemm_k<false, false, false, false><<<dim3(2, 2, CB * 2), 256, 0, stream>>>(
      Lm + 128 * CN, Wtri, nullptr, Ttmp, 128, 128, 128, CN, CN, 128,
      sPB, sPB, 32768LL, 1.0f, 2, 131328LL, 131328LL, 16384LL);
  gemm_k<false, false, false, false><<<dim3(2, 2, CB * 2), 256, 0, stream>>>(
      Wtri + 128 * CN + 128, Ttmp, nullptr, Wtri + 128 * CN, 128, 128, 128, CN, 128, CN,
      sPB, 32768LL, sPB, -1.0f, 2, 131328LL, 16384LL, 131328LL);
  gemm_k<false, false, false, false><<<dim3(4, 4, CB), 256, 0, stream>>>(
      Lm + 256 * CN, Wtri, nullptr, Ttmp, 256, 256, 256, CN, CN, 256,
      sPB, sPB, 65536LL, 1.0f, 1, 0, 0, 0);
  gemm_k<false, false, false, false><<<dim3(4, 4, CB), 256, 0, stream>>>(
      Wtri + 256 * CN + 256, Ttmp, nullptr, Wtri + 256 * CN, 256, 256, 256, CN, 256, CN,
      sPB, 65536LL, sPB, -1.0f, 1, 0, 0, 0);

  // prec = W^T W (SYRK)
  gemm_k<true, false, false, false, true><<<dim3(8, 8, CB), 256, 0, stream>>>(
      Wtri, Wtri, nullptr, prY, CN, CN, CN, CN, CN, CN, sPB, sPB, sPB, 1.0f, 1, 0, 0, 0);
  sdp_k<<<32, 256, 0, stream>>>(prY, sdp);
  pc_k<<<dim3(1024, CB), 256, 0, stream>>>(prY, sdp);

  fuse_sums<<<dim3(128, CB), 256, 0, stream>>>(covx, covr, prY, sums);
  alphas_k<<<1, 64, 0, stream>>>(sums, gam, alph);
  bfrow_k<<<dim3(CN, CB), 256, 0, stream>>>(covx, covr, prY, alph, AfF, dinv);
  norm_adj_k<<<dim3(1024, CB), 256, 0, stream>>>(AfF, dinv, Afp);
  xbuild_k<<<dim3(CN, CB), 256, 0, stream>>>(covx, covr, prY, lng, lnb, Xpk);

  wpack_k<<<dim3(24, 8), 256, 0, stream>>>(W0, w0t, CIN, CD, 786432LL);
  wpack_k<<<dim3(8, 8), 256, 0, stream>>>(W1, w1t, CD, CD, 262144LL);
  wpack_k<<<dim3(8, 8), 256, 0, stream>>>(W2, w2t, CD, CD, 262144LL);

  // GCN via bf16-split MFMA (128x128 tiles; orientation alternates, no transposes)
  gemm_mfma<false, false, true><<<dim3(64, 4, 1), 256, 0, stream>>>(
      w0t, Xpk, b0, Zt1, CIN, CIN, CIN, 8192, 0, 0, 0, 786432LL, 12582912LL, 4194304LL, 1.0f);
  gemm_mfma<false, true, false><<<dim3(4, 4, CB), 256, 0, stream>>>(
      Afp, Zt1, nullptr, H1p, CN, CN, 8192, CD, 262144LL, 512LL, 262144LL,
      4194304LL, 4194304LL, 4194304LL, 1.0f);
  gemm_mfma<false, false, true><<<dim3(64, 4, 1), 256, 0, stream>>>(
      w1t, H1p, b1, Zt2, CD, CD, CD, 8192, 0, 0, 0, 262144LL, 4194304LL, 4194304LL, 1.0f);
  gemm_mfma<false, true, false><<<dim3(4, 4, CB), 256, 0, stream>>>(
      Afp, Zt2, nullptr, H2p, CN, CN, 8192, CD, 262144LL, 512LL, 262144LL,
      4194304LL, 4194304LL, 4194304LL, 1.0f);
  gemm_mfma<false, false, true><<<dim3(64, 4, 1), 256, 0, stream>>>(
      w2t, H2p, b2, Zt3, CD, CD, CD, 8192, 0, 0, 0, 262144LL, 4194304LL, 4194304LL, 1.0f);
  gemm_mfma<true, true, false><<<dim3(4, 4, CB), 256, 0, stream>>>(
      Afp, Zt3, nullptr, Ha, CN, CN, 8192, CD, 262144LL, 512LL, 262144LL,
      4194304LL, 4194304LL, 0LL, 1.0f);

  gmean_k<<<dim3(2, CB), 256, 0, stream>>>(Ha, gm);
  final_k<<<CB, 256, 0, stream>>>(gm, Wc, bc, out);
}

// Round 16
// 1833.871 us; speedup vs baseline: 1.8822x; 1.0154x over previous
//
#include <hip/hip_runtime.h>
#include <math.h>

#define EPSF 1e-8f

constexpr int CB = 16;      // batch
constexpr int CT = 1024;    // time
constexpr int CN = 512;     // nodes
constexpr int CD = 512;     // hidden
constexpr int CIN = 1536;   // 3*N
constexpr int PB = CN * CN;
constexpr size_t SBTN = (size_t)CB * CT * CN;
constexpr size_t SBNN = (size_t)CB * PB;
constexpr long long PLX = 16777216LL;   // Xtp plane stride (u16 elems)

typedef __attribute__((ext_vector_type(8))) short bf16x8;
typedef __attribute__((ext_vector_type(4))) float f32x4;

__device__ inline unsigned short f2bf(float x) {   // RNE to bf16
  unsigned u = __float_as_uint(x);
  unsigned r = (u + 0x7fffu + ((u >> 16) & 1u)) >> 16;
  return (unsigned short)r;
}
__device__ inline float bf2f(unsigned short h) { return __uint_as_float(((unsigned)h) << 16); }

// ---------------- utility ----------------
__global__ void zero_k(float* p, int n) {
  int i = blockIdx.x * 256 + threadIdx.x;
  if (i < n) p[i] = 0.f;
}

// ---------------- column means ----------------
__global__ __launch_bounds__(256) void colmean_k(const float* __restrict__ x, float* __restrict__ ms) {
  int b = blockIdx.y;
  int n = blockIdx.x * 256 + threadIdx.x;
  int t0 = blockIdx.z * 256;
  const float* xb = x + (size_t)b * CT * CN + (size_t)t0 * CN + n;
  float s = 0.f;
  for (int t = 0; t < 256; ++t) s += xb[(size_t)t * CN];
  atomicAdd(&ms[b * CN + n], s);
}

// ---------------- centered transpose-pack: x (b,t,n) -> Xtp slot b (n,t) bf16 hi/lo ----------------
__global__ __launch_bounds__(256) void cpack_k(const float* __restrict__ x, const float* __restrict__ ms,
                                               unsigned short* __restrict__ Xtp) {
  __shared__ float t[64][65];
  int b = blockIdx.z, n0 = blockIdx.x * 64, t0 = blockIdx.y * 64;
  const float* xb = x + (size_t)b * CT * CN;
  for (int idx = threadIdx.x; idx < 4096; idx += 256) {
    int r = idx >> 6, c = idx & 63;
    t[r][c] = xb[(size_t)(t0 + r) * CN + n0 + c] - ms[b * CN + n0 + c] * (1.0f / CT);
  }
  __syncthreads();
  unsigned short* base = Xtp + (size_t)b * 524288;
  for (int idx = threadIdx.x; idx < 2048; idx += 256) {
    int nr = idx >> 5, tc = (idx & 31) * 2;
    float v0 = t[tc][nr], v1 = t[tc + 1][nr];
    unsigned short h0 = f2bf(v0), h1 = f2bf(v1);
    unsigned short l0 = f2bf(v0 - bf2f(h0)), l1 = f2bf(v1 - bf2f(h1));
    size_t off = (size_t)(n0 + nr) * 1024 + t0 + tc;
    *(unsigned int*)&base[off] = (unsigned int)h0 | ((unsigned int)h1 << 16);
    *(unsigned int*)&base[off + PLX] = (unsigned int)l0 | ((unsigned int)l1 << 16);
  }
}

// ---------------- Spearman ranks: merge-split bitonic, 8 columns/block ----------------
static __device__ inline unsigned long long shflx64(unsigned long long v, int m) {
  int lo = __shfl_xor((int)(unsigned)v, m, 64);
  int hi = __shfl_xor((int)(unsigned)(v >> 32), m, 64);
  return ((unsigned long long)(unsigned)hi << 32) | (unsigned)lo;
}

__global__ __launch_bounds__(256) void ranks_k(const float* __restrict__ x, unsigned short* __restrict__ Xtp) {
  int b = blockIdx.y;
  int n0 = blockIdx.x * 8;
  __shared__ float stage[8][1032];
  const float* xb = x + (size_t)b * CT * CN + n0;
  for (int t = threadIdx.x; t < 1024; t += 256) {
    float4 v0 = *(const float4*)&xb[(size_t)t * CN];
    float4 v1 = *(const float4*)&xb[(size_t)t * CN + 4];
    stage[0][t] = v0.x; stage[1][t] = v0.y; stage[2][t] = v0.z; stage[3][t] = v0.w;
    stage[4][t] = v1.x; stage[5][t] = v1.y; stage[6][t] = v1.z; stage[7][t] = v1.w;
  }
  __syncthreads();
  const int wave = threadIdx.x >> 6;
  const int lane = threadIdx.x & 63;
#pragma unroll 1
  for (int cc2 = 0; cc2 < 2; ++cc2) {
    const int c = wave * 2 + cc2;
    unsigned long long kv[16];
#pragma unroll
    for (int m = 0; m < 16; ++m) {
      int pos = m * 64 + lane;
      unsigned int u = __float_as_uint(stage[c][pos]);
      u = (u & 0x80000000u) ? ~u : (u | 0x80000000u);
      kv[m] = (((unsigned long long)u) << 32) | (unsigned)pos;
    }
#define CE_KV(a, bb, up) { bool sw_ = (up) ? (kv[a] > kv[bb]) : (kv[a] < kv[bb]); \
  if (sw_) { unsigned long long t_ = kv[a]; kv[a] = kv[bb]; kv[bb] = t_; } }
    // phase 1: in-lane bitonic sort of 16 (ascending), pure VALU
#pragma unroll
    for (int k2 = 2; k2 <= 16; k2 <<= 1) {
#pragma unroll
      for (int j2 = 8; j2 >= 1; j2 >>= 1) {
        if (j2 >= k2) continue;
#pragma unroll
        for (int t = 0; t < 16; ++t)
          if (!(t & j2)) { bool up2 = ((t & k2) == 0); CE_KV(t, t | j2, up2); }
      }
    }
    // phase 2: bitonic network over 64 sorted runs; CE = merge-split
#pragma unroll
    for (int k = 2; k <= 64; k <<= 1) {
#pragma unroll
      for (int j = 32; j >= 1; j >>= 1) {
        if (j >= k) continue;
        bool up = ((lane & k) == 0);
        bool isLow = ((lane & j) == 0);
        bool keepMin = (isLow == up);
        unsigned long long oth[16];
#pragma unroll
        for (int i = 0; i < 16; ++i) oth[i] = shflx64(kv[15 - i], j);
#pragma unroll
        for (int i = 0; i < 16; ++i) {
          unsigned long long o = oth[i];
          bool less = kv[i] < o;
          kv[i] = (less == keepMin) ? kv[i] : o;
        }
#pragma unroll
        for (int j2 = 8; j2 >= 1; j2 >>= 1)
#pragma unroll
          for (int t = 0; t < 16; ++t)
            if (!(t & j2)) CE_KV(t, t | j2, true);
      }
    }
#undef CE_KV
#pragma unroll
    for (int m = 0; m < 16; ++m) {
      unsigned int pos = (unsigned int)kv[m] & 1023u;
      stage[c][pos] = ((float)(lane * 16 + m + 1) - 512.5f) * (1.0f / 512.0f);
    }
  }
  __syncthreads();
  unsigned short* base = Xtp + (size_t)(16 + b) * 524288;
  for (int idx = threadIdx.x; idx < 4096; idx += 256) {
    int row = idx >> 9, t2 = (idx & 511) * 2;
    float v0 = stage[row][t2], v1 = stage[row][t2 + 1];
    unsigned short h0 = f2bf(v0), h1 = f2bf(v1);
    unsigned short l0 = f2bf(v0 - bf2f(h0)), l1 = f2bf(v1 - bf2f(h1));
    size_t off = (size_t)(n0 + row) * 1024 + t2;
    *(unsigned int*)&base[off] = (unsigned int)h0 | ((unsigned int)h1 << 16);
    *(unsigned int*)&base[off + PLX] = (unsigned int)l0 | ((unsigned int)l1 << 16);
  }
}

// ---------------- generic fp32 tiled GEMM (64x64 tile) + pair batching ----------------
template<bool TA, bool TB, bool ACC, bool RELU, bool SYRK = false>
__global__ __launch_bounds__(256) void gemm_k(
    const float* __restrict__ A, const float* __restrict__ B,
    const float* __restrict__ bias, float* __restrict__ C,
    int M, int Nc, int K, int lda, int ldb, int ldc,
    long long sA, long long sB, long long sC, float alpha,
    int pairs, long long pA, long long pB, long long pC) {
  __shared__ float As[16][68];
  __shared__ float Bs[16][68];
  const int bz = blockIdx.z;
  const int b = bz / pairs;
  const int p = bz - b * pairs;
  A += (size_t)b * sA + (size_t)p * pA;
  B += (size_t)b * sB + (size_t)p * pB;
  C += (size_t)b * sC + (size_t)p * pC;
  const int n0 = blockIdx.x * 64;
  const int m0 = blockIdx.y * 64;
  const int tid = threadIdx.x;
  const int tn = (tid & 15) * 4;
  const int tm = (tid >> 4) * 4;
  float acc[4][4];
#pragma unroll
  for (int i = 0; i < 4; ++i)
#pragma unroll
    for (int j = 0; j < 4; ++j) acc[i][j] = 0.f;

  const int kbeg = SYRK ? (m0 > n0 ? m0 : n0) : 0;
  for (int k0 = kbeg; k0 < K; k0 += 16) {
    if (TA) {
      const int lk = tid >> 4;
      const int lm = (tid & 15) * 4;
      const float4 v = *(const float4*)&A[(size_t)(k0 + lk) * lda + m0 + lm];
      *(float4*)&As[lk][lm] = v;
    } else {
      const int lm = tid >> 2;
      const int lk = (tid & 3) * 4;
      const float4 v = *(const float4*)&A[(size_t)(m0 + lm) * lda + k0 + lk];
      As[lk + 0][lm] = v.x; As[lk + 1][lm] = v.y; As[lk + 2][lm] = v.z; As[lk + 3][lm] = v.w;
    }
    if (TB) {
      const int ln = tid >> 2;
      const int lk = (tid & 3) * 4;
      const float4 v = *(const float4*)&B[(size_t)(n0 + ln) * ldb + k0 + lk];
      Bs[lk + 0][ln] = v.x; Bs[lk + 1][ln] = v.y; Bs[lk + 2][ln] = v.z; Bs[lk + 3][ln] = v.w;
    } else {
      const int lk = tid >> 4;
      const int ln = (tid & 15) * 4;
      const float4 v = *(const float4*)&B[(size_t)(k0 + lk) * ldb + n0 + ln];
      *(float4*)&Bs[lk][ln] = v;
    }
    __syncthreads();
#pragma unroll
    for (int kk = 0; kk < 16; ++kk) {
      const float4 a4 = *(const float4*)&As[kk][tm];
      const float4 b4 = *(const float4*)&Bs[kk][tn];
      const float av[4] = {a4.x, a4.y, a4.z, a4.w};
      const float bv[4] = {b4.x, b4.y, b4.z, b4.w};
#pragma unroll
      for (int i = 0; i < 4; ++i)
#pragma unroll
        for (int j = 0; j < 4; ++j) acc[i][j] = fmaf(av[i], bv[j], acc[i][j]);
    }
    __syncthreads();
  }
  float4 bb = make_float4(0.f, 0.f, 0.f, 0.f);
  if (bias) bb = *(const float4*)&bias[n0 + tn];
#pragma unroll
  for (int i = 0; i < 4; ++i) {
    size_t off = (size_t)(m0 + tm + i) * ldc + (n0 + tn);
    float4 v;
    v.x = alpha * acc[i][0] + bb.x;
    v.y = alpha * acc[i][1] + bb.y;
    v.z = alpha * acc[i][2] + bb.z;
    v.w = alpha * acc[i][3] + bb.w;
    if (ACC) {
      const float4 c0 = *(const float4*)&C[off];
      v.x += c0.x; v.y += c0.y; v.z += c0.z; v.w += c0.w;
    }
    if (RELU) {
      v.x = fmaxf(v.x, 0.f); v.y = fmaxf(v.y, 0.f);
      v.z = fmaxf(v.z, 0.f); v.w = fmaxf(v.w, 0.f);
    }
    *(float4*)&C[off] = v;
  }
}

// ---------------- bf16-split MFMA GEMM (128M x 128N tile, wave 64x64, K-step 32) ----------------
template<bool OUTF32, bool RELU, bool BIASROW>
__global__ __launch_bounds__(256, 2) void gemm_mfma(
    const unsigned short* __restrict__ A, const unsigned short* __restrict__ B,
    const float* __restrict__ bias, void* __restrict__ Cv,
    int K, int lda, int ldb, int ldc,
    long long sA, long long sB, long long sC,
    long long plA, long long plB, long long plC, float alpha) {
  __shared__ unsigned short As[2][4][128][8];
  __shared__ unsigned short Bs[2][4][128][8];
  const int bz = blockIdx.z;
  A += (size_t)bz * sA;
  B += (size_t)bz * sB;
  const int n0 = blockIdx.x * 128;
  const int m0 = blockIdx.y * 128;
  const int tid = threadIdx.x;
  const int wave = tid >> 6, lane = tid & 63;
  const int wm = wave & 1, wn = wave >> 1;
  const int l15 = lane & 15, quad = lane >> 4;
  const int r2 = tid >> 1;
  const int sp = (tid & 1) * 2;
  f32x4 acc[4][4];
#pragma unroll
  for (int i = 0; i < 4; ++i)
#pragma unroll
    for (int j = 0; j < 4; ++j) acc[i][j] = (f32x4){0.f, 0.f, 0.f, 0.f};

  for (int k0 = 0; k0 < K; k0 += 32) {
    const unsigned short* sa = A + (size_t)(m0 + r2) * lda + k0 + sp * 8;
    const unsigned short* sb = B + (size_t)(n0 + r2) * ldb + k0 + sp * 8;
    *(bf16x8*)&As[0][sp][r2][0]     = *(const bf16x8*)sa;
    *(bf16x8*)&As[0][sp + 1][r2][0] = *(const bf16x8*)(sa + 8);
    *(bf16x8*)&As[1][sp][r2][0]     = *(const bf16x8*)(sa + plA);
    *(bf16x8*)&As[1][sp + 1][r2][0] = *(const bf16x8*)(sa + plA + 8);
    *(bf16x8*)&Bs[0][sp][r2][0]     = *(const bf16x8*)sb;
    *(bf16x8*)&Bs[0][sp + 1][r2][0] = *(const bf16x8*)(sb + 8);
    *(bf16x8*)&Bs[1][sp][r2][0]     = *(const bf16x8*)(sb + plB);
    *(bf16x8*)&Bs[1][sp + 1][r2][0] = *(const bf16x8*)(sb + plB + 8);
    __syncthreads();
    bf16x8 ah[4], al[4], bh[4], bl[4];
#pragma unroll
    for (int i = 0; i < 4; ++i) {
      int m_l = wm * 64 + i * 16 + l15;
      int n_l = wn * 64 + i * 16 + l15;
      ah[i] = *(const bf16x8*)&As[0][quad][m_l][0];
      al[i] = *(const bf16x8*)&As[1][quad][m_l][0];
      bh[i] = *(const bf16x8*)&Bs[0][quad][n_l][0];
      bl[i] = *(const bf16x8*)&Bs[1][quad][n_l][0];
    }
#pragma unroll
    for (int i = 0; i < 4; ++i)
#pragma unroll
      for (int j = 0; j < 4; ++j) {
        acc[i][j] = __builtin_amdgcn_mfma_f32_16x16x32_bf16(ah[i], bh[j], acc[i][j], 0, 0, 0);
        acc[i][j] = __builtin_amdgcn_mfma_f32_16x16x32_bf16(ah[i], bl[j], acc[i][j], 0, 0, 0);
        acc[i][j] = __builtin_amdgcn_mfma_f32_16x16x32_bf16(al[i], bh[j], acc[i][j], 0, 0, 0);
      }
    __syncthreads();
  }
#pragma unroll
  for (int i = 0; i < 4; ++i)
#pragma unroll
    for (int j = 0; j < 4; ++j)
#pragma unroll
      for (int r = 0; r < 4; ++r) {
        int m_g = m0 + wm * 64 + i * 16 + quad * 4 + r;
        int n_g = n0 + wn * 64 + j * 16 + l15;
        float v = alpha * acc[i][j][r];
        if (BIASROW) v += bias[m_g];
        if (RELU) v = fmaxf(v, 0.f);
        if (OUTF32) {
          float* C = (float*)Cv + (size_t)bz * sC;
          C[(size_t)m_g * ldc + n_g] = v;
        } else {
          unsigned short* C = (unsigned short*)Cv + (size_t)bz * sC;
          unsigned short h = f2bf(v);
          C[(size_t)m_g * ldc + n_g] = h;
          C[(size_t)m_g * ldc + n_g + plC] = f2bf(v - bf2f(h));
        }
      }
}

// ---------------- weight pack: W (K x N f32) -> Wt (N x K bf16 hi/lo) ----------------
__global__ __launch_bounds__(256) void wpack_k(const float* __restrict__ W, unsigned short* __restrict__ Wt,
                                               int K, int N, long long plane) {
  __shared__ float t[64][65];
  int k0 = blockIdx.x * 64, n0 = blockIdx.y * 64;
  for (int idx = threadIdx.x; idx < 4096; idx += 256) {
    int r = idx >> 6, c = idx & 63;
    t[r][c] = W[(size_t)(k0 + r) * N + n0 + c];
  }
  __syncthreads();
  for (int idx = threadIdx.x; idx < 4096; idx += 256) {
    int r = idx >> 6, c = idx & 63;
    float v = t[c][r];
    unsigned short h = f2bf(v);
    size_t off = (size_t)(n0 + r) * K + k0 + c;
    Wt[off] = h;
    Wt[off + plane] = f2bf(v - bf2f(h));
  }
}

// ---------------- std vectors ----------------
__global__ void sds_k(const float* __restrict__ covx, const float* __restrict__ covr,
                      float* __restrict__ sdx, float* __restrict__ sdr) {
  int idx = blockIdx.x * 256 + threadIdx.x;
  int b = idx >> 9, i = idx & (CN - 1);
  size_t off = (size_t)b * PB + (size_t)i * (CN + 1);
  sdx[idx] = sqrtf(fmaxf(covx[off], EPSF));
  sdr[idx] = sqrtf(fmaxf(covr[off], EPSF));
}

__global__ __launch_bounds__(256) void prep_k(float* __restrict__ covx, float* __restrict__ covr,
                                              const float* __restrict__ sdx, const float* __restrict__ sdr,
                                              float* __restrict__ Lm, float* __restrict__ Wtri) {
  int b = blockIdx.y;
  int e = blockIdx.x * 256 + threadIdx.x;
  int i = e >> 9, j = e & (CN - 1);
  size_t off = (size_t)b * PB + e;
  float cx = covx[off], cr = covr[off];
  Lm[off] = cx + ((i == j) ? 0.001f : 0.0f);
  Wtri[off] = 0.f;
  if (i == j) {
    covx[off] = 1.0f; covr[off] = 1.0f;
  } else {
    covx[off] = cx / (sdx[b * CN + i] * sdx[b * CN + j]);
    covr[off] = cr / (sdr[b * CN + i] * sdr[b * CN + j]);
  }
}

// ---------------- register-tile LDL Cholesky + inverse (no LDS RMW in update path) ----------------
__global__ __launch_bounds__(256) void chol_diag(const float* __restrict__ A, float* __restrict__ Winv8, int kstep) {
  int b = blockIdx.x;
  const float* Ab = A + (size_t)b * PB + (size_t)(kstep * 64) * CN + kstep * 64;
  const int tid = threadIdx.x;
  const int r = tid >> 2;
  const int s = tid & 3;
  const int c0 = s * 16;
  __shared__ float colbuf[2][64];
  __shared__ float rowbuf[2][64];
  __shared__ float Lcol[64][65];    // Lcol[i][r] = frozen column i at row r
  float a[16];
#pragma unroll
  for (int q = 0; q < 4; ++q) {
    float4 v = *(const float4*)&Ab[(size_t)r * CN + c0 + q * 4];
    a[q * 4 + 0] = v.x; a[q * 4 + 1] = v.y; a[q * 4 + 2] = v.z; a[q * 4 + 3] = v.w;
  }
  // phase A: elimination with deferred scaling (unscaled columns)
  for (int i = 0; i < 64; ++i) {
    int par = i & 1;
    if (s == (i >> 4)) {
      float asel = a[0];
#pragma unroll
      for (int cc = 1; cc < 16; ++cc)
        if ((i & 15) == cc) asel = a[cc];
      colbuf[par][r] = asel;
      Lcol[i][r] = asel;
    }
    __syncthreads();
    float dinv = 1.0f / colbuf[par][i];
    float f = colbuf[par][r] * dinv;
#pragma unroll
    for (int cc = 0; cc < 16; ++cc) {
      int cgl = c0 + cc;
      float cv = colbuf[par][cgl];
      if (cgl > i) a[cc] = fmaf(-f, cv, a[cc]);
    }
  }
  __syncthreads();
  // phase B: V = M^{-1} (unit lower), rows in registers
  float v[16];
#pragma unroll
  for (int cc = 0; cc < 16; ++cc) v[cc] = (c0 + cc == r) ? 1.0f : 0.0f;
  for (int i = 0; i < 64; ++i) {
    int par = i & 1;
    if (r == i) {
#pragma unroll
      for (int cc = 0; cc < 16; ++cc) rowbuf[par][c0 + cc] = v[cc];
    }
    __syncthreads();
    float dinv = 1.0f / Lcol[i][i];
    float f = Lcol[i][r] * dinv;
    if (r > i) {
#pragma unroll
      for (int cc = 0; cc < 16; ++cc) {
        int cgl = c0 + cc;
        float rv = rowbuf[par][cgl];
        if (cgl <= i) v[cc] = fmaf(-f, rv, v[cc]);
      }
    }
  }
  // store: W[r][l] = V[r][l]/sqrt(d_r) lower, else 0 (coalesced float4)
  float* Wb = Winv8 + (size_t)b * 32768 + (size_t)kstep * 4096;
  float dr = sqrtf(Lcol[r][r]);
#pragma unroll
  for (int q = 0; q < 4; ++q) {
    float4 o;
    float t0v = (c0 + q * 4 + 0 <= r) ? v[q * 4 + 0] / dr : 0.0f;
    float t1v = (c0 + q * 4 + 1 <= r) ? v[q * 4 + 1] / dr : 0.0f;
    float t2v = (c0 + q * 4 + 2 <= r) ? v[q * 4 + 2] / dr : 0.0f;
    float t3v = (c0 + q * 4 + 3 <= r) ? v[q * 4 + 3] / dr : 0.0f;
    o.x = t0v; o.y = t1v; o.z = t2v; o.w = t3v;
    *(float4*)&Wb[r * 64 + c0 + q * 4] = o;
  }
}

__global__ void wdiag_k(const float* __restrict__ Winv8, float* __restrict__ W) {
  int e = blockIdx.x * 256 + threadIdx.x;
  int b = e >> 15;
  int r = e & 32767;
  int blk = r >> 12;
  int idx = r & 4095;
  int row = idx >> 6, col = idx & 63;
  W[(size_t)b * PB + (size_t)(blk * 64 + row) * CN + blk * 64 + col] = Winv8[e];
}

__global__ void sdp_k(const float* __restrict__ prec, float* __restrict__ sdp) {
  int idx = blockIdx.x * 256 + threadIdx.x;
  int b = idx >> 9, i = idx & (CN - 1);
  sdp[idx] = sqrtf(fmaxf(prec[(size_t)b * PB + (size_t)i * (CN + 1)], EPSF));
}

__global__ __launch_bounds__(256) void pc_k(float* __restrict__ prec, const float* __restrict__ sdp) {
  int b = blockIdx.y;
  int e = blockIdx.x * 256 + threadIdx.x;
  int i = e >> 9, j = e & (CN - 1);
  size_t off = (size_t)b * PB + e;
  float arg = (i == j) ? 1.0f : -prec[off] / (sdp[b * CN + i] * sdp[b * CN + j]);
  prec[off] = tanhf(arg);
}

// ---------------- similarity sums over strict upper triangle ----------------
__global__ __launch_bounds__(256) void fuse_sums(const float* __restrict__ Pm, const float* __restrict__ Sm,
                                                 const float* __restrict__ Cm, float* __restrict__ sums) {
  int b = blockIdx.y;
  int base = blockIdx.x * 2048;
  float pp = 0, ss = 0, cc = 0, ps = 0, pc = 0, sc = 0;
  for (int u = 0; u < 8; ++u) {
    int e = base + u * 256 + threadIdx.x;
    int i = e >> 9, j = e & (CN - 1);
    if (j > i) {
      size_t off = (size_t)b * PB + e;
      float p = Pm[off];
      float s = Sm[off];
      float cv = Cm[off];
      pp += p * p; ss += s * s; cc += cv * cv;
      ps += p * s; pc += p * cv; sc += s * cv;
    }
  }
  __shared__ float red[256];
  float vals[6] = {pp, ss, cc, ps, pc, sc};
#pragma unroll
  for (int v = 0; v < 6; ++v) {
    red[threadIdx.x] = vals[v];
    __syncthreads();
    for (int s2 = 128; s2 > 0; s2 >>= 1) {
      if (threadIdx.x < s2) red[threadIdx.x] += red[threadIdx.x + s2];
      __syncthreads();
    }
    if (threadIdx.x == 0) atomicAdd(&sums[b * 6 + v], red[0]);
    __syncthreads();
  }
}

__global__ void alphas_k(const float* __restrict__ sums, const float* __restrict__ gamma,
                         float* __restrict__ alph) {
  int b = threadIdx.x;
  if (b >= CB) return;
  float sPP = sums[b * 6 + 0], sSS = sums[b * 6 + 1], sCC = sums[b * 6 + 2];
  float sPS = sums[b * 6 + 3], sPC = sums[b * 6 + 4], sSC = sums[b * 6 + 5];
  float numP = 0.5f * (sPS + sPC), numS = 0.5f * (sPS + sSC), numC = 0.5f * (sPC + sSC);
  float noP = 0.5f * sqrtf(sSS + sCC + 2.f * sSC);
  float noS = 0.5f * sqrtf(sPP + sCC + 2.f * sPC);
  float noC = 0.5f * sqrtf(sPP + sSS + 2.f * sPS);
  float dP = fmaxf(sqrtf(sPP), EPSF) * fmaxf(noP, EPSF);
  float dS = fmaxf(sqrtf(sSS), EPSF) * fmaxf(noS, EPSF);
  float dC = fmaxf(sqrtf(sCC), EPSF) * fmaxf(noC, EPSF);
  float g = gamma[0];
  float aP = g * numP / dP, aS = g * numS / dS, aC = g * numC / dC;
  float m = fmaxf(fmaxf(aP, aS), aC);
  float eP = expf(aP - m), eS = expf(aS - m), eC = expf(aC - m);
  float inv = 1.f / (eP + eS + eC);
  alph[b * 3 + 0] = eP * inv;
  alph[b * 3 + 1] = eS * inv;
  alph[b * 3 + 2] = eC * inv;
}

// ---------------- fused: A_fused row + rowsum + LayerNorm features + bf16 pack ----------------
// Thread tid holds P/S/C at j=tid and j=256+tid in registers -> both bfrow and
// xbuild outputs computed in one pass (reduction trees identical to the split kernels).
__global__ __launch_bounds__(256) void bfxb_k(const float* __restrict__ Pm, const float* __restrict__ Sm,
                                              const float* __restrict__ Cm, const float* __restrict__ alph,
                                              const float* __restrict__ lng, const float* __restrict__ lnb,
                                              float* __restrict__ Af, float* __restrict__ dinv,
                                              unsigned short* __restrict__ Xpk) {
  int b = blockIdx.y, n = blockIdx.x;
  int tid = threadIdx.x;
  size_t base = (size_t)b * PB + (size_t)n * CN;
  float v[6];
  v[0] = Pm[base + tid];       // k=0: part0 j=tid
  v[1] = Pm[base + 256 + tid]; // k=1: part0 j=256+tid
  v[2] = Sm[base + tid];       // k=2
  v[3] = Sm[base + 256 + tid]; // k=3
  v[4] = Cm[base + tid];       // k=4
  v[5] = Cm[base + 256 + tid]; // k=5
  float ls = 0.f, lq = 0.f;
#pragma unroll
  for (int k = 0; k < 6; ++k) { ls += v[k]; lq += v[k] * v[k]; }
  // Af row (bfrow semantics)
  float aP = alph[b * 3 + 0], aS = alph[b * 3 + 1], aC = alph[b * 3 + 2];
  float af0 = (n == tid) ? 1.0f : aP * v[0] + aS * v[2] + aC * v[4];
  float af1 = (n == 256 + tid) ? 1.0f : aP * v[1] + aS * v[3] + aC * v[5];
  Af[base + tid] = af0;
  Af[base + 256 + tid] = af1;
  float vsum = af0 + af1;
  __shared__ float red[256];
  __shared__ float rs[256], rq[256];
  red[tid] = vsum; rs[tid] = ls; rq[tid] = lq;
  __syncthreads();
  for (int s = 128; s > 0; s >>= 1) {
    if (tid < s) {
      red[tid] += red[tid + s];
      rs[tid] += rs[tid + s];
      rq[tid] += rq[tid + s];
    }
    __syncthreads();
  }
  if (tid == 0) dinv[b * CN + n] = 1.0f / sqrtf(fmaxf(red[0], EPSF));
  float mu = rs[0] * (1.0f / CIN);
  float var = rq[0] * (1.0f / CIN) - mu * mu;
  float rstd = 1.0f / sqrtf(var + 1e-5f);
  const size_t XPLANE = (size_t)CB * CN * CIN;
  unsigned short* Xrow = Xpk + ((size_t)b * CN + n) * CIN;
#pragma unroll
  for (int k = 0; k < 6; ++k) {
    int pos = k * 256 + tid;
    float o = (v[k] - mu) * rstd * lng[pos] + lnb[pos];
    unsigned short h = f2bf(o);
    Xrow[pos] = h;
    Xrow[pos + XPLANE] = f2bf(o - bf2f(h));
  }
}

// normalize + pack to bf16 hi/lo planes
__global__ __launch_bounds__(256) void norm_adj_k(const float* __restrict__ AfF, const float* __restrict__ dinv,
                                                  unsigned short* __restrict__ Afp) {
  int b = blockIdx.y;
  int e = blockIdx.x * 256 + threadIdx.x;
  int i = e >> 9, j = e & (CN - 1);
  size_t off = (size_t)b * PB + e;
  float v = AfF[off] * dinv[b * CN + i] * dinv[b * CN + j];
  unsigned short h = f2bf(v);
  Afp[off] = h;
  Afp[off + SBNN] = f2bf(v - bf2f(h));
}

// ---------------- head: mean-pool + classifier + sigmoid (fused) ----------------
__global__ __launch_bounds__(256) void head_k(const float* __restrict__ H, const float* __restrict__ Wc,
                                              const float* __restrict__ bc, float* __restrict__ out) {
  int b = blockIdx.x;
  int d = threadIdx.x;
  const float* Hb = H + (size_t)b * CN * CD;
  float s0 = 0.f, s1 = 0.f;
  for (int n = 0; n < CN; ++n) {
    s0 += Hb[(size_t)n * CD + d];
    s1 += Hb[(size_t)n * CD + 256 + d];
  }
  float g0 = s0 * (1.0f / CN), g1 = s1 * (1.0f / CN);
  __shared__ float red[256];
  red[d] = g0 * Wc[d] + g1 * Wc[256 + d];
  __syncthreads();
  for (int k = 128; k > 0; k >>= 1) {
    if (d < k) red[d] += red[d + k];
    __syncthreads();
  }
  if (d == 0) {
    float z = red[0] + bc[0];
    out[b] = 1.0f / (1.0f + expf(-z));
  }
}

// ---------------- launcher ----------------
extern "C" void kernel_launch(void* const* d_in, const int* in_sizes, int n_in,
                              void* d_out, int out_size, void* d_ws, size_t ws_size,
                              hipStream_t stream) {
  const float* x    = (const float*)d_in[0];
  const float* gam  = (const float*)d_in[1];
  const float* lng  = (const float*)d_in[2];
  const float* lnb  = (const float*)d_in[3];
  const float* W0   = (const float*)d_in[4];
  const float* b0   = (const float*)d_in[5];
  const float* W1   = (const float*)d_in[6];
  const float* b1   = (const float*)d_in[7];
  const float* W2   = (const float*)d_in[8];
  const float* b2   = (const float*)d_in[9];
  const float* Wc   = (const float*)d_in[10];
  const float* bc   = (const float*)d_in[11];
  float* out = (float*)d_out;
  float* ws = (float*)d_ws;

  unsigned short* Xtp = (unsigned short*)ws;
  float* Winv8 = ws;                      // Xtp dead after cov
  float* Ttmp  = ws + 524288;
  float* covx  = ws + 16777216;
  float* covr  = covx + SBNN;
  float* Lm    = covx + 2 * SBNN;
  float* Wtri  = covx + 3 * SBNN;
  float* prY   = covx + 4 * SBNN;
  float* sdx   = covx + 5 * SBNN;
  float* sdr   = sdx + 8192;
  float* sdp   = sdr + 8192;
  float* dinv  = sdp + 8192;
  float* gm    = dinv + 8192;
  float* ms    = gm + 8192;
  float* sums  = ms + 8192;
  float* alph  = sums + 96;

  unsigned short* Xpk  = (unsigned short*)ws;
  unsigned short* Afp  = (unsigned short*)(ws + 12582912);
  float*          AfF  = Lm;
  unsigned short* w0t  = (unsigned short*)Lm;
  unsigned short* w1t  = (unsigned short*)(Lm + 1048576);
  unsigned short* w2t  = (unsigned short*)(Lm + 1572864);
  unsigned short* Zt1  = (unsigned short*)prY;
  unsigned short* Zt2  = (unsigned short*)Wtri;
  unsigned short* Zt3  = (unsigned short*)prY;
  unsigned short* H1p  = (unsigned short*)covx;
  unsigned short* H2p  = (unsigned short*)covr;
  float*          Ha   = covx;

  const float covscale = (float)(1.0 / 1023.00000001);
  const long long sPB = (long long)PB;

  zero_k<<<(8288 + 255) / 256, 256, 0, stream>>>(ms, 8288);
  colmean_k<<<dim3(2, CB, 4), 256, 0, stream>>>(x, ms);
  cpack_k<<<dim3(8, 16, CB), 256, 0, stream>>>(x, ms, Xtp);
  ranks_k<<<dim3(CN / 8, CB), 256, 0, stream>>>(x, Xtp);

  // both covariances via bf16-split MFMA (128x128 tiles, 512 blocks)
  gemm_mfma<true, false, false><<<dim3(4, 4, 32), 256, 0, stream>>>(
      Xtp, Xtp, nullptr, covx, 1024, 1024, 1024, CN,
      524288LL, 524288LL, sPB, PLX, PLX, 0LL, covscale);
  sds_k<<<32, 256, 0, stream>>>(covx, covr, sdx, sdr);
  prep_k<<<dim3(1024, CB), 256, 0, stream>>>(covx, covr, sdx, sdr, Lm, Wtri);

  // blocked Cholesky (NB=64), register-tile diag kernels
  for (int k = 0; k < 8; ++k) {
    chol_diag<<<CB, 256, 0, stream>>>(Lm, Winv8, k);
    int Mt = CN - 64 * (k + 1);
    if (Mt > 0) {
      float* Apan = Lm + (size_t)(k + 1) * 64 * CN + k * 64;
      float* Atrl = Lm + (size_t)(k + 1) * 64 * CN + (k + 1) * 64;
      gemm_k<false, true, false, false><<<dim3(1, Mt / 64, CB), 256, 0, stream>>>(
          Apan, Winv8 + (size_t)k * 4096, nullptr, Apan, Mt, 64, 64, CN, 64, CN,
          sPB, 32768LL, sPB, 1.0f, 1, 0, 0, 0);
      gemm_k<false, true, true, false><<<dim3(Mt / 64, Mt / 64, CB), 256, 0, stream>>>(
          Apan, Apan, nullptr, Atrl, Mt, Mt, 64, CN, CN, CN,
          sPB, sPB, sPB, -1.0f, 1, 0, 0, 0);
    }
  }

  // W = L^{-1}: diag blocks + divide-and-conquer merges
  wdiag_k<<<2048, 256, 0, stream>>>(Winv8, Wtri);
  gemm_k<false, false, false, false><<<dim3(1, 1, CB * 4), 256, 0, stream>>>(
      Lm + 64 * CN, Wtri, nullptr, Ttmp, 64, 64, 64, CN, CN, 64,
      sPB, sPB, 16384LL, 1.0f, 4, 65664LL, 65664LL, 4096LL);
  gemm_k<false, false, false, false><<<dim3(1, 1, CB * 4), 256, 0, stream>>>(
      Wtri + 64 * CN + 64, Ttmp, nullptr, Wtri + 64 * CN, 64, 64, 64, CN, 64, CN,
      sPB, 16384LL, sPB, -1.0f, 4, 65664LL, 4096LL, 65664LL);
  gemm_k<false, false, false, false><<<dim3(2, 2, CB * 2), 256, 0, stream>>>(
      Lm + 128 * CN, Wtri, nullptr, Ttmp, 128, 128, 128, CN, CN, 128,
      sPB, sPB, 32768LL, 1.0f, 2, 131328LL, 131328LL, 16384LL);
  gemm_k<false, false, false, false><<<dim3(2, 2, CB * 2), 256, 0, stream>>>(
      Wtri + 128 * CN + 128, Ttmp, nullptr, Wtri + 128 * CN, 128, 128, 128, CN, 128, CN,
      sPB, 32768LL, sPB, -1.0f, 2, 131328LL, 16384LL, 131328LL);
  gemm_k<false, false, false, false><<<dim3(4, 4, CB), 256, 0, stream>>>(
      Lm + 256 * CN, Wtri, nullptr, Ttmp, 256, 256, 256, CN, CN, 256,
      sPB, sPB, 65536LL, 1.0f, 1, 0, 0, 0);
  gemm_k<false, false, false, false><<<dim3(4, 4, CB), 256, 0, stream>>>(
      Wtri + 256 * CN + 256, Ttmp, nullptr, Wtri + 256 * CN, 256, 256, 256, CN, 256, CN,
      sPB, 65536LL, sPB, -1.0f, 1, 0, 0, 0);

  // prec = W^T W (SYRK)
  gemm_k<true, false, false, false, true><<<dim3(8, 8, CB), 256, 0, stream>>>(
      Wtri, Wtri, nullptr, prY, CN, CN, CN, CN, CN, CN, sPB, sPB, sPB, 1.0f, 1, 0, 0, 0);
  sdp_k<<<32, 256, 0, stream>>>(prY, sdp);
  pc_k<<<dim3(1024, CB), 256, 0, stream>>>(prY, sdp);

  fuse_sums<<<dim3(128, CB), 256, 0, stream>>>(covx, covr, prY, sums);
  alphas_k<<<1, 64, 0, stream>>>(sums, gam, alph);
  bfxb_k<<<dim3(CN, CB), 256, 0, stream>>>(covx, covr, prY, alph, lng, lnb, AfF, dinv, Xpk);
  norm_adj_k<<<dim3(1024, CB), 256, 0, stream>>>(AfF, dinv, Afp);

  wpack_k<<<dim3(24, 8), 256, 0, stream>>>(W0, w0t, CIN, CD, 786432LL);
  wpack_k<<<dim3(8, 8), 256, 0, stream>>>(W1, w1t, CD, CD, 262144LL);
  wpack_k<<<dim3(8, 8), 256, 0, stream>>>(W2, w2t, CD, CD, 262144LL);

  // GCN via bf16-split MFMA (128x128 tiles; orientation alternates, no transposes)
  gemm_mfma<false, false, true><<<dim3(64, 4, 1), 256, 0, stream>>>(
      w0t, Xpk, b0, Zt1, CIN, CIN, CIN, 8192, 0, 0, 0, 786432LL, 12582912LL, 4194304LL, 1.0f);
  gemm_mfma<false, true, false><<<dim3(4, 4, CB), 256, 0, stream>>>(
      Afp, Zt1, nullptr, H1p, CN, CN, 8192, CD, 262144LL, 512LL, 262144LL,
      4194304LL, 4194304LL, 4194304LL, 1.0f);
  gemm_mfma<false, false, true><<<dim3(64, 4, 1), 256, 0, stream>>>(
      w1t, H1p, b1, Zt2, CD, CD, CD, 8192, 0, 0, 0, 262144LL, 4194304LL, 4194304LL, 1.0f);
  gemm_mfma<false, true, false><<<dim3(4, 4, CB), 256, 0, stream>>>(
      Afp, Zt2, nullptr, H2p, CN, CN, 8192, CD, 262144LL, 512LL, 262144LL,
      4194304LL, 4194304LL, 4194304LL, 1.0f);
  gemm_mfma<false, false, true><<<dim3(64, 4, 1), 256, 0, stream>>>(
      w2t, H2p, b2, Zt3, CD, CD, CD, 8192, 0, 0, 0, 262144LL, 4194304LL, 4194304LL, 1.0f);
  gemm_mfma<true, true, false><<<dim3(4, 4, CB), 256, 0, stream>>>(
      Afp, Zt3, nullptr, Ha, CN, CN, 8192, CD, 262144LL, 512LL, 262144LL,
      4194304LL, 4194304LL, 0LL, 1.0f);

  head_k<<<CB, 256, 0, stream>>>(Ha, Wc, bc, out);
}